// Round 2
// baseline (1757.371 us; speedup 1.0000x reference)
//
#include <hip/hip_runtime.h>
#include <math.h>

#define DH 128

// ---------------- CSR build ----------------

__global__ void k_hist(const int* __restrict__ ei, int* __restrict__ deg, int E_) {
    int e = blockIdx.x * blockDim.x + threadIdx.x;
    if (e >= E_) return;
    atomicAdd(&deg[ei[E_ + e]], 1);   // dst = ei[1][e]
}

__global__ void k_scan(const int* __restrict__ deg, int* __restrict__ rowptr,
                       int* __restrict__ cursor, int N_) {
    __shared__ int part[1024];
    int t = threadIdx.x;
    int chunk = (N_ + 1023) >> 10;
    int lo = t * chunk;
    int hi = min(N_, lo + chunk);
    int s = 0;
    for (int i = lo; i < hi; ++i) s += deg[i];
    part[t] = s;
    __syncthreads();
    // Hillis-Steele inclusive scan over 1024 partials
    for (int off = 1; off < 1024; off <<= 1) {
        int v = (t >= off) ? part[t - off] : 0;
        __syncthreads();
        part[t] += v;
        __syncthreads();
    }
    int run = part[t] - s;   // exclusive prefix at chunk start
    for (int i = lo; i < hi; ++i) {
        rowptr[i] = run;
        cursor[i] = run;
        run += deg[i];
    }
    if (t == 1023) rowptr[N_] = part[1023];
}

__global__ void k_scatter(const int* __restrict__ ei, int* __restrict__ cursor,
                          int* __restrict__ col, int E_) {
    int e = blockIdx.x * blockDim.x + threadIdx.x;
    if (e >= E_) return;
    int d = ei[E_ + e];
    int p = atomicAdd(&cursor[d], 1);
    col[p] = ei[e];   // src
}

// ---------------- weight transpose (WT[k][j] = W[j][k]) ----------------

__global__ void k_transpose(const float* __restrict__ w0, const float* __restrict__ w1,
                            const float* __restrict__ w2, const float* __restrict__ w3,
                            const float* __restrict__ w4, const float* __restrict__ w5,
                            float* __restrict__ wt) {
    int m = blockIdx.y;
    const float* s;
    switch (m) {
        case 0: s = w0; break; case 1: s = w1; break; case 2: s = w2; break;
        case 3: s = w3; break; case 4: s = w4; break; default: s = w5; break;
    }
    float* d = wt + (size_t)m * DH * DH;
    int t = blockIdx.x * 256 + threadIdx.x;   // 0..16383
    int k = t & (DH - 1);
    int j = t >> 7;
    d[k * DH + j] = s[j * DH + k];
}

// ---------------- mean aggregation over CSR (32 lanes per node) ----------------

__global__ void k_agg(const float* __restrict__ F, const int* __restrict__ rowptr,
                      const int* __restrict__ col, float* __restrict__ out, int N_) {
    int g = (blockIdx.x * blockDim.x + threadIdx.x) >> 5;   // node
    int l = threadIdx.x & 31;
    if (g >= N_) return;
    int lo = rowptr[g], hi = rowptr[g + 1];
    float4 acc0 = {0.f, 0.f, 0.f, 0.f};
    float4 acc1 = {0.f, 0.f, 0.f, 0.f};
    int j = lo;
    for (; j + 1 < hi; j += 2) {
        int s0 = col[j], s1 = col[j + 1];
        float4 v0 = *reinterpret_cast<const float4*>(F + (size_t)s0 * DH + l * 4);
        float4 v1 = *reinterpret_cast<const float4*>(F + (size_t)s1 * DH + l * 4);
        acc0.x += v0.x; acc0.y += v0.y; acc0.z += v0.z; acc0.w += v0.w;
        acc1.x += v1.x; acc1.y += v1.y; acc1.z += v1.z; acc1.w += v1.w;
    }
    if (j < hi) {
        int s0 = col[j];
        float4 v0 = *reinterpret_cast<const float4*>(F + (size_t)s0 * DH + l * 4);
        acc0.x += v0.x; acc0.y += v0.y; acc0.z += v0.z; acc0.w += v0.w;
    }
    float inv = 1.0f / fmaxf((float)(hi - lo), 1.0f);
    float4 r;
    r.x = (acc0.x + acc1.x) * inv;
    r.y = (acc0.y + acc1.y) * inv;
    r.z = (acc0.z + acc1.z) * inv;
    r.w = (acc0.w + acc1.w) * inv;
    *reinterpret_cast<float4*>(out + (size_t)g * DH + l * 4) = r;
}

// ---------------- dual GEMM: 4 cols x 8 rows per thread ----------------

__device__ __forceinline__ void fma4(float4& a, float s, const float4& w) {
    a.x = fmaf(s, w.x, a.x);
    a.y = fmaf(s, w.y, a.y);
    a.z = fmaf(s, w.z, a.z);
    a.w = fmaf(s, w.w, a.w);
}

// acc[n] (cols j0..j0+3) += rows[n0..n0+7] of rowbase times WT cols j0..j0+3
__device__ __forceinline__ void gemm_pass4(const float* __restrict__ rowbase,
                                           const float* __restrict__ WT,
                                           int j0, float4 acc[8]) {
    for (int k = 0; k < DH; k += 4) {
        float4 w0 = *reinterpret_cast<const float4*>(WT + (size_t)(k + 0) * DH + j0);
        float4 w1 = *reinterpret_cast<const float4*>(WT + (size_t)(k + 1) * DH + j0);
        float4 w2 = *reinterpret_cast<const float4*>(WT + (size_t)(k + 2) * DH + j0);
        float4 w3 = *reinterpret_cast<const float4*>(WT + (size_t)(k + 3) * DH + j0);
#pragma unroll
        for (int n = 0; n < 8; ++n) {
            float4 av = *reinterpret_cast<const float4*>(rowbase + (size_t)n * DH + k);
            fma4(acc[n], av.x, w0);
            fma4(acc[n], av.y, w1);
            fma4(acc[n], av.z, w2);
            fma4(acc[n], av.w, w3);
        }
    }
}

template <int ACT>   // 0 = none, 1 = relu
__global__ void k_gemm2(const float* __restrict__ A, const float* __restrict__ B,
                        const float* __restrict__ WaT, const float* __restrict__ WbT,
                        const float* __restrict__ bias, float* __restrict__ out, int N_) {
    int jt = threadIdx.x & 31;    // 32 col-groups of 4
    int rg = threadIdx.x >> 5;    // 8 row-groups of 8 rows
    int j0 = jt * 4;
    int n0 = blockIdx.x * 64 + rg * 8;
    if (n0 >= N_) return;
    float4 acc[8];
    float4 bv = *reinterpret_cast<const float4*>(bias + j0);
#pragma unroll
    for (int n = 0; n < 8; ++n) acc[n] = bv;
    gemm_pass4(A + (size_t)n0 * DH, WaT, j0, acc);
    gemm_pass4(B + (size_t)n0 * DH, WbT, j0, acc);
#pragma unroll
    for (int n = 0; n < 8; ++n) {
        float4 v = acc[n];
        if (ACT == 1) {
            v.x = fmaxf(v.x, 0.f); v.y = fmaxf(v.y, 0.f);
            v.z = fmaxf(v.z, 0.f); v.w = fmaxf(v.w, 0.f);
        }
        *reinterpret_cast<float4*>(out + (size_t)(n0 + n) * DH + j0) = v;
    }
}

// ---------------- RNN step: out = tanh(H2@Wi^T + bi + bh) @ Wo^T + bo ----------------

__global__ void k_rnn(const float* __restrict__ H2, const float* __restrict__ WiT,
                      const float* __restrict__ bi, const float* __restrict__ bh,
                      const float* __restrict__ WoT, const float* __restrict__ bo,
                      float* __restrict__ out, int N_) {
    __shared__ float hid[64][DH];
    int jt = threadIdx.x & 31;
    int rg = threadIdx.x >> 5;
    int j0 = jt * 4;
    int n0 = blockIdx.x * 64 + rg * 8;
    bool active = (n0 < N_);
    float4 acc[8];
    if (active) {
        float4 b1 = *reinterpret_cast<const float4*>(bi + j0);
        float4 b2 = *reinterpret_cast<const float4*>(bh + j0);
        float4 bv;
        bv.x = b1.x + b2.x; bv.y = b1.y + b2.y;
        bv.z = b1.z + b2.z; bv.w = b1.w + b2.w;
#pragma unroll
        for (int n = 0; n < 8; ++n) acc[n] = bv;
        gemm_pass4(H2 + (size_t)n0 * DH, WiT, j0, acc);
#pragma unroll
        for (int n = 0; n < 8; ++n) {
            float4 t;
            t.x = tanhf(acc[n].x); t.y = tanhf(acc[n].y);
            t.z = tanhf(acc[n].z); t.w = tanhf(acc[n].w);
            *reinterpret_cast<float4*>(&hid[rg * 8 + n][j0]) = t;
        }
    }
    __syncthreads();
    if (!active) return;
    float4 bov = *reinterpret_cast<const float4*>(bo + j0);
#pragma unroll
    for (int n = 0; n < 8; ++n) acc[n] = bov;
    for (int k = 0; k < DH; k += 4) {
        float4 w0 = *reinterpret_cast<const float4*>(WoT + (size_t)(k + 0) * DH + j0);
        float4 w1 = *reinterpret_cast<const float4*>(WoT + (size_t)(k + 1) * DH + j0);
        float4 w2 = *reinterpret_cast<const float4*>(WoT + (size_t)(k + 2) * DH + j0);
        float4 w3 = *reinterpret_cast<const float4*>(WoT + (size_t)(k + 3) * DH + j0);
#pragma unroll
        for (int n = 0; n < 8; ++n) {
            float4 hv = *reinterpret_cast<const float4*>(&hid[rg * 8 + n][k]);
            fma4(acc[n], hv.x, w0);
            fma4(acc[n], hv.y, w1);
            fma4(acc[n], hv.z, w2);
            fma4(acc[n], hv.w, w3);
        }
    }
#pragma unroll
    for (int n = 0; n < 8; ++n)
        *reinterpret_cast<float4*>(out + (size_t)(n0 + n) * DH + j0) = acc[n];
}

// ---------------- row-normalize: outn = row / max(||row||, eps) ----------------

__global__ void k_norm(const float* __restrict__ in, float* __restrict__ outn, int N_) {
    int g = (blockIdx.x * blockDim.x + threadIdx.x) >> 5;
    int l = threadIdx.x & 31;
    if (g >= N_) return;
    float4 v = *reinterpret_cast<const float4*>(in + (size_t)g * DH + l * 4);
    float s = v.x * v.x + v.y * v.y + v.z * v.z + v.w * v.w;
#pragma unroll
    for (int off = 16; off; off >>= 1) s += __shfl_xor(s, off, 32);
    float inv = 1.0f / fmaxf(sqrtf(s), 1e-6f);
    v.x *= inv; v.y *= inv; v.z *= inv; v.w *= inv;
    *reinterpret_cast<float4*>(outn + (size_t)g * DH + l * 4) = v;
}

// ---------------- decode: sigmoid(dot(normalized rows)) ----------------

__global__ void k_decode(const float* __restrict__ Fn, const int* __restrict__ di,
                         float* __restrict__ res, int Q_) {
    int q = (blockIdx.x * blockDim.x + threadIdx.x) >> 5;
    int l = threadIdx.x & 31;
    if (q >= Q_) return;
    int ia = di[q];
    int ib = di[Q_ + q];
    float4 a = *reinterpret_cast<const float4*>(Fn + (size_t)ia * DH + l * 4);
    float4 b = *reinterpret_cast<const float4*>(Fn + (size_t)ib * DH + l * 4);
    float s = a.x * b.x + a.y * b.y + a.z * b.z + a.w * b.w;
#pragma unroll
    for (int off = 16; off; off >>= 1) s += __shfl_xor(s, off, 32);
    if (l == 0) res[q] = 1.0f / (1.0f + expf(-s));
}

// ---------------- launch ----------------

extern "C" void kernel_launch(void* const* d_in, const int* in_sizes, int n_in,
                              void* d_out, int out_size, void* d_ws, size_t ws_size,
                              hipStream_t stream) {
    const float* x   = (const float*)d_in[0];
    const int*   ei  = (const int*)d_in[1];
    const int*   di  = (const int*)d_in[2];
    const float* W1l = (const float*)d_in[3];
    const float* b1l = (const float*)d_in[4];
    const float* W1r = (const float*)d_in[5];
    const float* W2l = (const float*)d_in[6];
    const float* b2l = (const float*)d_in[7];
    const float* W2r = (const float*)d_in[8];
    const float* Wi  = (const float*)d_in[9];
    const float* bi  = (const float*)d_in[10];
    // d_in[11] = Wh: unused (hidden state is zeros -> only bh contributes)
    const float* bh  = (const float*)d_in[12];
    const float* Wo  = (const float*)d_in[13];
    const float* bo  = (const float*)d_in[14];
    float* outq = (float*)d_out;

    int N_ = in_sizes[0] / DH;
    int E_ = in_sizes[1] / 2;
    int Q_ = in_sizes[2] / 2;

    char* base = (char*)d_ws;
    size_t o = 0;
    auto alloc = [&](size_t bytes) -> void* {
        o = (o + 511) & ~(size_t)511;
        void* p = base + o;
        o += bytes;
        return p;
    };
    int*   deg    = (int*)alloc((size_t)N_ * 4);
    int*   rowptr = (int*)alloc((size_t)(N_ + 1) * 4);
    int*   cursor = (int*)alloc((size_t)N_ * 4);
    int*   col    = (int*)alloc((size_t)E_ * 4);
    float* wt     = (float*)alloc((size_t)6 * DH * DH * 4);
    float* bufA   = (float*)alloc((size_t)N_ * DH * 4);
    float* bufB   = (float*)alloc((size_t)N_ * DH * 4);
    float* bufC   = (float*)alloc((size_t)N_ * DH * 4);

    const float* W1lT = wt + 0 * DH * DH;
    const float* W1rT = wt + 1 * DH * DH;
    const float* W2lT = wt + 2 * DH * DH;
    const float* W2rT = wt + 3 * DH * DH;
    const float* WiT  = wt + 4 * DH * DH;
    const float* WoT  = wt + 5 * DH * DH;

    hipMemsetAsync(deg, 0, (size_t)N_ * 4, stream);
    k_hist<<<(E_ + 255) / 256, 256, 0, stream>>>(ei, deg, E_);
    k_scan<<<1, 1024, 0, stream>>>(deg, rowptr, cursor, N_);
    k_scatter<<<(E_ + 255) / 256, 256, 0, stream>>>(ei, cursor, col, E_);
    dim3 tg(64, 6);
    k_transpose<<<tg, 256, 0, stream>>>(W1l, W1r, W2l, W2r, Wi, Wo, wt);

    // layer 1: mean-agg(x) -> bufA ; h = relu(bufA@W1l^T + b1l + x@W1r^T) -> bufB
    k_agg<<<(N_ + 7) / 8, 256, 0, stream>>>(x, rowptr, col, bufA, N_);
    k_gemm2<1><<<(N_ + 63) / 64, 256, 0, stream>>>(bufA, x, W1lT, W1rT, b1l, bufB, N_);
    // layer 2: mean-agg(h) -> bufA ; h2 = bufA@W2l^T + b2l + h@W2r^T -> bufC
    k_agg<<<(N_ + 7) / 8, 256, 0, stream>>>(bufB, rowptr, col, bufA, N_);
    k_gemm2<0><<<(N_ + 63) / 64, 256, 0, stream>>>(bufA, bufB, W2lT, W2rT, b2l, bufC, N_);
    // rnn: out = tanh(h2@Wi^T + bi + bh)@Wo^T + bo -> bufB
    k_rnn<<<(N_ + 63) / 64, 256, 0, stream>>>(bufC, WiT, bi, bh, WoT, bo, bufB, N_);
    // normalize rows -> bufA ; decode -> d_out
    k_norm<<<(N_ + 7) / 8, 256, 0, stream>>>(bufB, bufA, N_);
    k_decode<<<(Q_ + 7) / 8, 256, 0, stream>>>(bufA, di, outq, Q_);
}

// Round 5
// 1624.013 us; speedup vs baseline: 1.0821x; 1.0821x over previous
//
#include <hip/hip_runtime.h>
#include <math.h>

#define DH 128
#define NXCD 8

// ---------------- CSR build (XCD-sliced by dst range) ----------------
// Each XCD-slice handles only edges whose dst is in its 1/8 node range, so
// deg/cursor atomics and col[] writes fall in a contiguous region that stays
// resident in that XCD's L2 (kills the 16x write amplification measured in
// round 2: WRITE_SIZE 194 MB for a 12.8 MB col array). Cost: the dst stream
// is read 8x, but it is L3-resident and int4-vectorized.

__global__ void k_hist(const int* __restrict__ ei, int* __restrict__ deg, int E_, int N_) {
    int slice = blockIdx.x & (NXCD - 1);      // heuristic: blockIdx round-robins XCDs
    int blk   = blockIdx.x >> 3;
    int nblk  = gridDim.x >> 3;
    int lo_n = slice * (N_ >> 3);
    int hi_n = (slice == NXCD - 1) ? N_ : lo_n + (N_ >> 3);
    const int* dsts = ei + E_;
    int E4 = E_ >> 2;
    for (int e4 = blk * blockDim.x + threadIdx.x; e4 < E4; e4 += nblk * blockDim.x) {
        int4 d4 = *reinterpret_cast<const int4*>(dsts + e4 * 4);
        if (d4.x >= lo_n && d4.x < hi_n) atomicAdd(&deg[d4.x], 1);
        if (d4.y >= lo_n && d4.y < hi_n) atomicAdd(&deg[d4.y], 1);
        if (d4.z >= lo_n && d4.z < hi_n) atomicAdd(&deg[d4.z], 1);
        if (d4.w >= lo_n && d4.w < hi_n) atomicAdd(&deg[d4.w], 1);
    }
    // tail
    if (blk == 0 && threadIdx.x < (E_ & 3)) {
        int d = dsts[E4 * 4 + threadIdx.x];
        if (d >= lo_n && d < hi_n) atomicAdd(&deg[d], 1);
    }
}

__global__ void k_scan(const int* __restrict__ deg, int* __restrict__ rowptr,
                       int* __restrict__ cursor, int N_) {
    __shared__ int part[1024];
    int t = threadIdx.x;
    int chunk = (N_ + 1023) >> 10;
    int lo = t * chunk;
    int hi = min(N_, lo + chunk);
    int s = 0;
    for (int i = lo; i < hi; ++i) s += deg[i];
    part[t] = s;
    __syncthreads();
    for (int off = 1; off < 1024; off <<= 1) {
        int v = (t >= off) ? part[t - off] : 0;
        __syncthreads();
        part[t] += v;
        __syncthreads();
    }
    int run = part[t] - s;   // exclusive prefix at chunk start
    for (int i = lo; i < hi; ++i) {
        rowptr[i] = run;
        cursor[i] = run;
        run += deg[i];
    }
    if (t == 1023) rowptr[N_] = part[1023];
}

__global__ void k_scatter(const int* __restrict__ ei, int* __restrict__ cursor,
                          int* __restrict__ col, int E_, int N_) {
    int slice = blockIdx.x & (NXCD - 1);
    int blk   = blockIdx.x >> 3;
    int nblk  = gridDim.x >> 3;
    int lo_n = slice * (N_ >> 3);
    int hi_n = (slice == NXCD - 1) ? N_ : lo_n + (N_ >> 3);
    const int* dsts = ei + E_;
    int E4 = E_ >> 2;
    for (int e4 = blk * blockDim.x + threadIdx.x; e4 < E4; e4 += nblk * blockDim.x) {
        int4 d4 = *reinterpret_cast<const int4*>(dsts + e4 * 4);
        int e = e4 * 4;
        if (d4.x >= lo_n && d4.x < hi_n) { int p = atomicAdd(&cursor[d4.x], 1); col[p] = ei[e + 0]; }
        if (d4.y >= lo_n && d4.y < hi_n) { int p = atomicAdd(&cursor[d4.y], 1); col[p] = ei[e + 1]; }
        if (d4.z >= lo_n && d4.z < hi_n) { int p = atomicAdd(&cursor[d4.z], 1); col[p] = ei[e + 2]; }
        if (d4.w >= lo_n && d4.w < hi_n) { int p = atomicAdd(&cursor[d4.w], 1); col[p] = ei[e + 3]; }
    }
    // tail
    if (blk == 0 && threadIdx.x < (E_ & 3)) {
        int e = E4 * 4 + threadIdx.x;
        int d = dsts[e];
        if (d >= lo_n && d < hi_n) { int p = atomicAdd(&cursor[d], 1); col[p] = ei[e]; }
    }
}

// ---------------- weight transpose (WT[k][j] = W[j][k]) ----------------

__global__ void k_transpose(const float* __restrict__ w0, const float* __restrict__ w1,
                            const float* __restrict__ w2, const float* __restrict__ w3,
                            const float* __restrict__ w4, const float* __restrict__ w5,
                            float* __restrict__ wt) {
    int m = blockIdx.y;
    const float* s;
    switch (m) {
        case 0: s = w0; break; case 1: s = w1; break; case 2: s = w2; break;
        case 3: s = w3; break; case 4: s = w4; break; default: s = w5; break;
    }
    float* d = wt + (size_t)m * DH * DH;
    int t = blockIdx.x * 256 + threadIdx.x;   // 0..16383
    int k = t & (DH - 1);
    int j = t >> 7;
    d[k * DH + j] = s[j * DH + k];
}

// ---------------- mean aggregation over CSR (32 lanes per node) ----------------
// 4-deep unroll: 4 outstanding 512B gathers per 32-lane group to hide L2/L3
// hit latency (avg degree 32 -> 8 main-loop iterations).

__global__ __launch_bounds__(256) void k_agg(const float* __restrict__ F,
                                             const int* __restrict__ rowptr,
                                             const int* __restrict__ col,
                                             float* __restrict__ out, int N_) {
    int g = (blockIdx.x * blockDim.x + threadIdx.x) >> 5;   // node
    int l = threadIdx.x & 31;
    if (g >= N_) return;
    int lo = rowptr[g], hi = rowptr[g + 1];
    float4 acc0 = {0.f, 0.f, 0.f, 0.f};
    float4 acc1 = {0.f, 0.f, 0.f, 0.f};
    float4 acc2 = {0.f, 0.f, 0.f, 0.f};
    float4 acc3 = {0.f, 0.f, 0.f, 0.f};
    int j = lo;
    for (; j + 3 < hi; j += 4) {
        int s0 = col[j], s1 = col[j + 1], s2 = col[j + 2], s3 = col[j + 3];
        float4 v0 = *reinterpret_cast<const float4*>(F + (size_t)s0 * DH + l * 4);
        float4 v1 = *reinterpret_cast<const float4*>(F + (size_t)s1 * DH + l * 4);
        float4 v2 = *reinterpret_cast<const float4*>(F + (size_t)s2 * DH + l * 4);
        float4 v3 = *reinterpret_cast<const float4*>(F + (size_t)s3 * DH + l * 4);
        acc0.x += v0.x; acc0.y += v0.y; acc0.z += v0.z; acc0.w += v0.w;
        acc1.x += v1.x; acc1.y += v1.y; acc1.z += v1.z; acc1.w += v1.w;
        acc2.x += v2.x; acc2.y += v2.y; acc2.z += v2.z; acc2.w += v2.w;
        acc3.x += v3.x; acc3.y += v3.y; acc3.z += v3.z; acc3.w += v3.w;
    }
    for (; j < hi; ++j) {
        int s0 = col[j];
        float4 v0 = *reinterpret_cast<const float4*>(F + (size_t)s0 * DH + l * 4);
        acc0.x += v0.x; acc0.y += v0.y; acc0.z += v0.z; acc0.w += v0.w;
    }
    float inv = 1.0f / fmaxf((float)(hi - lo), 1.0f);
    float4 r;
    r.x = (acc0.x + acc1.x + acc2.x + acc3.x) * inv;
    r.y = (acc0.y + acc1.y + acc2.y + acc3.y) * inv;
    r.z = (acc0.z + acc1.z + acc2.z + acc3.z) * inv;
    r.w = (acc0.w + acc1.w + acc2.w + acc3.w) * inv;
    *reinterpret_cast<float4*>(out + (size_t)g * DH + l * 4) = r;
}

// ---------------- dual GEMM: 4 cols x 8 rows per thread ----------------

__device__ __forceinline__ void fma4(float4& a, float s, const float4& w) {
    a.x = fmaf(s, w.x, a.x);
    a.y = fmaf(s, w.y, a.y);
    a.z = fmaf(s, w.z, a.z);
    a.w = fmaf(s, w.w, a.w);
}

__device__ __forceinline__ void gemm_pass4(const float* __restrict__ rowbase,
                                           const float* __restrict__ WT,
                                           int j0, float4 acc[8]) {
    for (int k = 0; k < DH; k += 4) {
        float4 w0 = *reinterpret_cast<const float4*>(WT + (size_t)(k + 0) * DH + j0);
        float4 w1 = *reinterpret_cast<const float4*>(WT + (size_t)(k + 1) * DH + j0);
        float4 w2 = *reinterpret_cast<const float4*>(WT + (size_t)(k + 2) * DH + j0);
        float4 w3 = *reinterpret_cast<const float4*>(WT + (size_t)(k + 3) * DH + j0);
#pragma unroll
        for (int n = 0; n < 8; ++n) {
            float4 av = *reinterpret_cast<const float4*>(rowbase + (size_t)n * DH + k);
            fma4(acc[n], av.x, w0);
            fma4(acc[n], av.y, w1);
            fma4(acc[n], av.z, w2);
            fma4(acc[n], av.w, w3);
        }
    }
}

template <int ACT>   // 0 = none, 1 = relu
__global__ __launch_bounds__(256) void k_gemm2(const float* __restrict__ A,
                                               const float* __restrict__ B,
                                               const float* __restrict__ WaT,
                                               const float* __restrict__ WbT,
                                               const float* __restrict__ bias,
                                               float* __restrict__ out, int N_) {
    int jt = threadIdx.x & 31;    // 32 col-groups of 4
    int rg = threadIdx.x >> 5;    // 8 row-groups of 8 rows
    int j0 = jt * 4;
    int n0 = blockIdx.x * 64 + rg * 8;
    if (n0 >= N_) return;
    float4 acc[8];
    float4 bv = *reinterpret_cast<const float4*>(bias + j0);
#pragma unroll
    for (int n = 0; n < 8; ++n) acc[n] = bv;
    gemm_pass4(A + (size_t)n0 * DH, WaT, j0, acc);
    gemm_pass4(B + (size_t)n0 * DH, WbT, j0, acc);
#pragma unroll
    for (int n = 0; n < 8; ++n) {
        float4 v = acc[n];
        if (ACT == 1) {
            v.x = fmaxf(v.x, 0.f); v.y = fmaxf(v.y, 0.f);
            v.z = fmaxf(v.z, 0.f); v.w = fmaxf(v.w, 0.f);
        }
        *reinterpret_cast<float4*>(out + (size_t)(n0 + n) * DH + j0) = v;
    }
}

// ---- RNN + normalize fused: t = tanh(H2@Wi^T+bi+bh); o = t@Wo^T+bo; out = o/max(||o||,eps)

__global__ __launch_bounds__(256) void k_rnn(const float* __restrict__ H2,
                                             const float* __restrict__ WiT,
                                             const float* __restrict__ bi,
                                             const float* __restrict__ bh,
                                             const float* __restrict__ WoT,
                                             const float* __restrict__ bo,
                                             float* __restrict__ out, int N_) {
    __shared__ float hid[64][DH];
    int jt = threadIdx.x & 31;
    int rg = threadIdx.x >> 5;
    int j0 = jt * 4;
    int n0 = blockIdx.x * 64 + rg * 8;
    bool active = (n0 < N_);
    float4 acc[8];
    if (active) {
        float4 b1 = *reinterpret_cast<const float4*>(bi + j0);
        float4 b2 = *reinterpret_cast<const float4*>(bh + j0);
        float4 bv;
        bv.x = b1.x + b2.x; bv.y = b1.y + b2.y;
        bv.z = b1.z + b2.z; bv.w = b1.w + b2.w;
#pragma unroll
        for (int n = 0; n < 8; ++n) acc[n] = bv;
        gemm_pass4(H2 + (size_t)n0 * DH, WiT, j0, acc);
#pragma unroll
        for (int n = 0; n < 8; ++n) {
            float4 t;
            t.x = tanhf(acc[n].x); t.y = tanhf(acc[n].y);
            t.z = tanhf(acc[n].z); t.w = tanhf(acc[n].w);
            *reinterpret_cast<float4*>(&hid[rg * 8 + n][j0]) = t;
        }
    }
    __syncthreads();
    if (!active) return;
    float4 bov = *reinterpret_cast<const float4*>(bo + j0);
#pragma unroll
    for (int n = 0; n < 8; ++n) acc[n] = bov;
    for (int k = 0; k < DH; k += 4) {
        float4 w0 = *reinterpret_cast<const float4*>(WoT + (size_t)(k + 0) * DH + j0);
        float4 w1 = *reinterpret_cast<const float4*>(WoT + (size_t)(k + 1) * DH + j0);
        float4 w2 = *reinterpret_cast<const float4*>(WoT + (size_t)(k + 2) * DH + j0);
        float4 w3 = *reinterpret_cast<const float4*>(WoT + (size_t)(k + 3) * DH + j0);
#pragma unroll
        for (int n = 0; n < 8; ++n) {
            float4 hv = *reinterpret_cast<const float4*>(&hid[rg * 8 + n][k]);
            fma4(acc[n], hv.x, w0);
            fma4(acc[n], hv.y, w1);
            fma4(acc[n], hv.z, w2);
            fma4(acc[n], hv.w, w3);
        }
    }
    // fused row-normalize: the 32 jt-threads of one rg are one contiguous
    // 32-lane shuffle group and jointly hold cols 0..127 of rows n0..n0+7.
#pragma unroll
    for (int n = 0; n < 8; ++n) {
        float4 v = acc[n];
        float s = v.x * v.x + v.y * v.y + v.z * v.z + v.w * v.w;
#pragma unroll
        for (int off = 16; off; off >>= 1) s += __shfl_xor(s, off, 32);
        float inv = 1.0f / fmaxf(sqrtf(s), 1e-6f);
        v.x *= inv; v.y *= inv; v.z *= inv; v.w *= inv;
        *reinterpret_cast<float4*>(out + (size_t)(n0 + n) * DH + j0) = v;
    }
}

// ---------------- decode: sigmoid(dot(normalized rows)) ----------------

__global__ __launch_bounds__(256) void k_decode(const float* __restrict__ Fn,
                                                const int* __restrict__ di,
                                                float* __restrict__ res, int Q_) {
    int q = (blockIdx.x * blockDim.x + threadIdx.x) >> 5;
    int l = threadIdx.x & 31;
    if (q >= Q_) return;
    int ia = di[q];
    int ib = di[Q_ + q];
    float4 a = *reinterpret_cast<const float4*>(Fn + (size_t)ia * DH + l * 4);
    float4 b = *reinterpret_cast<const float4*>(Fn + (size_t)ib * DH + l * 4);
    float s = a.x * b.x + a.y * b.y + a.z * b.z + a.w * b.w;
#pragma unroll
    for (int off = 16; off; off >>= 1) s += __shfl_xor(s, off, 32);
    if (l == 0) res[q] = 1.0f / (1.0f + expf(-s));
}

// ---------------- launch ----------------

extern "C" void kernel_launch(void* const* d_in, const int* in_sizes, int n_in,
                              void* d_out, int out_size, void* d_ws, size_t ws_size,
                              hipStream_t stream) {
    const float* x   = (const float*)d_in[0];
    const int*   ei  = (const int*)d_in[1];
    const int*   di  = (const int*)d_in[2];
    const float* W1l = (const float*)d_in[3];
    const float* b1l = (const float*)d_in[4];
    const float* W1r = (const float*)d_in[5];
    const float* W2l = (const float*)d_in[6];
    const float* b2l = (const float*)d_in[7];
    const float* W2r = (const float*)d_in[8];
    const float* Wi  = (const float*)d_in[9];
    const float* bi  = (const float*)d_in[10];
    // d_in[11] = Wh: unused (hidden state is zeros -> only bh contributes)
    const float* bh  = (const float*)d_in[12];
    const float* Wo  = (const float*)d_in[13];
    const float* bo  = (const float*)d_in[14];
    float* outq = (float*)d_out;

    int N_ = in_sizes[0] / DH;
    int E_ = in_sizes[1] / 2;
    int Q_ = in_sizes[2] / 2;

    char* base = (char*)d_ws;
    size_t o = 0;
    auto alloc = [&](size_t bytes) -> void* {
        o = (o + 511) & ~(size_t)511;
        void* p = base + o;
        o += bytes;
        return p;
    };
    int*   deg    = (int*)alloc((size_t)N_ * 4);
    int*   rowptr = (int*)alloc((size_t)(N_ + 1) * 4);
    int*   cursor = (int*)alloc((size_t)N_ * 4);
    int*   col    = (int*)alloc((size_t)E_ * 4);
    float* wt     = (float*)alloc((size_t)6 * DH * DH * 4);
    float* bufA   = (float*)alloc((size_t)N_ * DH * 4);
    float* bufB   = (float*)alloc((size_t)N_ * DH * 4);
    float* bufC   = (float*)alloc((size_t)N_ * DH * 4);

    const float* W1lT = wt + 0 * DH * DH;
    const float* W1rT = wt + 1 * DH * DH;
    const float* W2lT = wt + 2 * DH * DH;
    const float* W2rT = wt + 3 * DH * DH;
    const float* WiT  = wt + 4 * DH * DH;
    const float* WoT  = wt + 5 * DH * DH;

    hipMemsetAsync(deg, 0, (size_t)N_ * 4, stream);
    k_hist<<<8192, 256, 0, stream>>>(ei, deg, E_, N_);
    k_scan<<<1, 1024, 0, stream>>>(deg, rowptr, cursor, N_);
    k_scatter<<<8192, 256, 0, stream>>>(ei, cursor, col, E_, N_);
    dim3 tg(64, 6);
    k_transpose<<<tg, 256, 0, stream>>>(W1l, W1r, W2l, W2r, Wi, Wo, wt);

    // layer 1: mean-agg(x) -> bufA ; h = relu(bufA@W1l^T + b1l + x@W1r^T) -> bufB
    k_agg<<<(N_ + 7) / 8, 256, 0, stream>>>(x, rowptr, col, bufA, N_);
    k_gemm2<1><<<(N_ + 63) / 64, 256, 0, stream>>>(bufA, x, W1lT, W1rT, b1l, bufB, N_);
    // layer 2: mean-agg(h) -> bufA ; h2 = bufA@W2l^T + b2l + h@W2r^T -> bufC
    k_agg<<<(N_ + 7) / 8, 256, 0, stream>>>(bufB, rowptr, col, bufA, N_);
    k_gemm2<0><<<(N_ + 63) / 64, 256, 0, stream>>>(bufA, bufB, W2lT, W2rT, b2l, bufC, N_);
    // rnn + fused normalize -> bufB
    k_rnn<<<(N_ + 63) / 64, 256, 0, stream>>>(bufC, WiT, bi, bh, WoT, bo, bufB, N_);
    // decode -> d_out
    k_decode<<<(Q_ + 7) / 8, 256, 0, stream>>>(bufB, di, outq, Q_);
}

// Round 6
// 1392.616 us; speedup vs baseline: 1.2619x; 1.1662x over previous
//
#include <hip/hip_runtime.h>
#include <math.h>

#define DH 128
#define NXCD 8
#define STILE 1024   // scan tile: 256 threads x int4

// ---------------- CSR build (XCD-sliced by dst range) ----------------
// Each XCD-slice handles only edges whose dst is in its 1/8 node range, so
// deg/cursor atomics and col[] writes fall in a contiguous region that stays
// resident in that XCD's L2 (kills the 16x write amplification measured in
// round 2: WRITE_SIZE 194 MB for a 12.8 MB col array).

__global__ void k_hist(const int* __restrict__ ei, int* __restrict__ deg, int E_, int N_) {
    int slice = blockIdx.x & (NXCD - 1);      // heuristic: blockIdx round-robins XCDs
    int blk   = blockIdx.x >> 3;
    int nblk  = gridDim.x >> 3;
    int lo_n = slice * (N_ >> 3);
    int hi_n = (slice == NXCD - 1) ? N_ : lo_n + (N_ >> 3);
    const int* dsts = ei + E_;
    int E4 = E_ >> 2;
    for (int e4 = blk * blockDim.x + threadIdx.x; e4 < E4; e4 += nblk * blockDim.x) {
        int4 d4 = *reinterpret_cast<const int4*>(dsts + e4 * 4);
        if (d4.x >= lo_n && d4.x < hi_n) atomicAdd(&deg[d4.x], 1);
        if (d4.y >= lo_n && d4.y < hi_n) atomicAdd(&deg[d4.y], 1);
        if (d4.z >= lo_n && d4.z < hi_n) atomicAdd(&deg[d4.z], 1);
        if (d4.w >= lo_n && d4.w < hi_n) atomicAdd(&deg[d4.w], 1);
    }
    if (blk == 0 && threadIdx.x < (E_ & 3)) {
        int d = dsts[E4 * 4 + threadIdx.x];
        if (d >= lo_n && d < hi_n) atomicAdd(&deg[d], 1);
    }
}

// ---------------- hierarchical scan (replaces 230us single-block k_scan) ----

// A: per-tile exclusive scan into excl[], tile total into tsum[]
__global__ __launch_bounds__(256) void k_scan1(const int* __restrict__ deg,
                                               int* __restrict__ excl,
                                               int* __restrict__ tsum, int N_) {
    __shared__ int wsum[4];
    int t = threadIdx.x;
    int idx = blockIdx.x * STILE + t * 4;
    int4 v = {0, 0, 0, 0};
    if (idx + 3 < N_) {
        v = *reinterpret_cast<const int4*>(deg + idx);
    } else {
        if (idx + 0 < N_) v.x = deg[idx + 0];
        if (idx + 1 < N_) v.y = deg[idx + 1];
        if (idx + 2 < N_) v.z = deg[idx + 2];
        if (idx + 3 < N_) v.w = deg[idx + 3];
    }
    int s0 = v.x, s1 = s0 + v.y, s2 = s1 + v.z, s3 = s2 + v.w;   // inclusive in quad
    int lane = t & 63, w = t >> 6;
    int inc = s3;
    for (int off = 1; off < 64; off <<= 1) {
        int u = __shfl_up(inc, off, 64);
        if (lane >= off) inc += u;
    }
    if (lane == 63) wsum[w] = inc;
    __syncthreads();
    int woff = 0;
    for (int i = 0; i < w; ++i) woff += wsum[i];
    int exq = woff + inc - s3;   // exclusive prefix of this quad
    int4 e;
    e.x = exq; e.y = exq + s0; e.z = exq + s1; e.w = exq + s2;
    if (idx + 3 < N_) {
        *reinterpret_cast<int4*>(excl + idx) = e;
    } else {
        if (idx + 0 < N_) excl[idx + 0] = e.x;
        if (idx + 1 < N_) excl[idx + 1] = e.y;
        if (idx + 2 < N_) excl[idx + 2] = e.z;
        if (idx + 3 < N_) excl[idx + 3] = e.w;
    }
    if (t == 255) tsum[blockIdx.x] = woff + inc;
}

// B: one block scans tile totals (ntiles <= 1024) -> exclusive toff[], total -> rowptr[N]
__global__ void k_scan2(const int* __restrict__ tsum, int* __restrict__ toff,
                        int ntiles, int* __restrict__ rowptrN) {
    __shared__ int sh[1024];
    int t = threadIdx.x;
    int v = (t < ntiles) ? tsum[t] : 0;
    sh[t] = v;
    __syncthreads();
    for (int off = 1; off < 1024; off <<= 1) {
        int u = (t >= off) ? sh[t - off] : 0;
        __syncthreads();
        sh[t] += u;
        __syncthreads();
    }
    if (t < ntiles) toff[t] = sh[t] - v;
    if (t == 1023) *rowptrN = sh[1023];
}

// C: add tile offsets; materialize rowptr & cursor
__global__ __launch_bounds__(256) void k_scan3(int* __restrict__ rowptr,
                                               int* __restrict__ cursor,
                                               const int* __restrict__ toff, int N_) {
    int off = toff[blockIdx.x];
    int idx = blockIdx.x * STILE + threadIdx.x * 4;
    if (idx + 3 < N_) {
        int4 e = *reinterpret_cast<int4*>(rowptr + idx);
        e.x += off; e.y += off; e.z += off; e.w += off;
        *reinterpret_cast<int4*>(rowptr + idx) = e;
        *reinterpret_cast<int4*>(cursor + idx) = e;
    } else {
        for (int i = 0; i < 4; ++i)
            if (idx + i < N_) { int e = rowptr[idx + i] + off; rowptr[idx + i] = e; cursor[idx + i] = e; }
    }
}

__global__ void k_scatter(const int* __restrict__ ei, int* __restrict__ cursor,
                          int* __restrict__ col, int E_, int N_) {
    int slice = blockIdx.x & (NXCD - 1);
    int blk   = blockIdx.x >> 3;
    int nblk  = gridDim.x >> 3;
    int lo_n = slice * (N_ >> 3);
    int hi_n = (slice == NXCD - 1) ? N_ : lo_n + (N_ >> 3);
    const int* dsts = ei + E_;
    int E4 = E_ >> 2;
    for (int e4 = blk * blockDim.x + threadIdx.x; e4 < E4; e4 += nblk * blockDim.x) {
        int4 d4 = *reinterpret_cast<const int4*>(dsts + e4 * 4);
        int e = e4 * 4;
        if (d4.x >= lo_n && d4.x < hi_n) { int p = atomicAdd(&cursor[d4.x], 1); col[p] = ei[e + 0]; }
        if (d4.y >= lo_n && d4.y < hi_n) { int p = atomicAdd(&cursor[d4.y], 1); col[p] = ei[e + 1]; }
        if (d4.z >= lo_n && d4.z < hi_n) { int p = atomicAdd(&cursor[d4.z], 1); col[p] = ei[e + 2]; }
        if (d4.w >= lo_n && d4.w < hi_n) { int p = atomicAdd(&cursor[d4.w], 1); col[p] = ei[e + 3]; }
    }
    if (blk == 0 && threadIdx.x < (E_ & 3)) {
        int e = E4 * 4 + threadIdx.x;
        int d = dsts[e];
        if (d >= lo_n && d < hi_n) { int p = atomicAdd(&cursor[d], 1); col[p] = ei[e]; }
    }
}

// ---------------- weight transpose (WT[k][j] = W[j][k]) ----------------

__global__ void k_transpose(const float* __restrict__ w0, const float* __restrict__ w1,
                            const float* __restrict__ w2, const float* __restrict__ w3,
                            const float* __restrict__ w4, const float* __restrict__ w5,
                            float* __restrict__ wt) {
    int m = blockIdx.y;
    const float* s;
    switch (m) {
        case 0: s = w0; break; case 1: s = w1; break; case 2: s = w2; break;
        case 3: s = w3; break; case 4: s = w4; break; default: s = w5; break;
    }
    float* d = wt + (size_t)m * DH * DH;
    int t = blockIdx.x * 256 + threadIdx.x;   // 0..16383
    int k = t & (DH - 1);
    int j = t >> 7;
    d[k * DH + j] = s[j * DH + k];
}

// ---------------- mean aggregation over CSR (32 lanes per node) ----------------

__global__ __launch_bounds__(256) void k_agg(const float* __restrict__ F,
                                             const int* __restrict__ rowptr,
                                             const int* __restrict__ col,
                                             float* __restrict__ out, int N_) {
    int g = (blockIdx.x * blockDim.x + threadIdx.x) >> 5;   // node
    int l = threadIdx.x & 31;
    if (g >= N_) return;
    int lo = rowptr[g], hi = rowptr[g + 1];
    float4 acc0 = {0.f, 0.f, 0.f, 0.f};
    float4 acc1 = {0.f, 0.f, 0.f, 0.f};
    float4 acc2 = {0.f, 0.f, 0.f, 0.f};
    float4 acc3 = {0.f, 0.f, 0.f, 0.f};
    int j = lo;
    for (; j + 3 < hi; j += 4) {
        int s0 = col[j], s1 = col[j + 1], s2 = col[j + 2], s3 = col[j + 3];
        float4 v0 = *reinterpret_cast<const float4*>(F + (size_t)s0 * DH + l * 4);
        float4 v1 = *reinterpret_cast<const float4*>(F + (size_t)s1 * DH + l * 4);
        float4 v2 = *reinterpret_cast<const float4*>(F + (size_t)s2 * DH + l * 4);
        float4 v3 = *reinterpret_cast<const float4*>(F + (size_t)s3 * DH + l * 4);
        acc0.x += v0.x; acc0.y += v0.y; acc0.z += v0.z; acc0.w += v0.w;
        acc1.x += v1.x; acc1.y += v1.y; acc1.z += v1.z; acc1.w += v1.w;
        acc2.x += v2.x; acc2.y += v2.y; acc2.z += v2.z; acc2.w += v2.w;
        acc3.x += v3.x; acc3.y += v3.y; acc3.z += v3.z; acc3.w += v3.w;
    }
    for (; j < hi; ++j) {
        int s0 = col[j];
        float4 v0 = *reinterpret_cast<const float4*>(F + (size_t)s0 * DH + l * 4);
        acc0.x += v0.x; acc0.y += v0.y; acc0.z += v0.z; acc0.w += v0.w;
    }
    float inv = 1.0f / fmaxf((float)(hi - lo), 1.0f);
    float4 r;
    r.x = (acc0.x + acc1.x + acc2.x + acc3.x) * inv;
    r.y = (acc0.y + acc1.y + acc2.y + acc3.y) * inv;
    r.z = (acc0.z + acc1.z + acc2.z + acc3.z) * inv;
    r.w = (acc0.w + acc1.w + acc2.w + acc3.w) * inv;
    *reinterpret_cast<float4*>(out + (size_t)g * DH + l * 4) = r;
}

// ---------------- dual GEMM: 4 cols x 8 rows per thread ----------------

__device__ __forceinline__ void fma4(float4& a, float s, const float4& w) {
    a.x = fmaf(s, w.x, a.x);
    a.y = fmaf(s, w.y, a.y);
    a.z = fmaf(s, w.z, a.z);
    a.w = fmaf(s, w.w, a.w);
}

__device__ __forceinline__ void gemm_pass4(const float* __restrict__ rowbase,
                                           const float* __restrict__ WT,
                                           int j0, float4 acc[8]) {
    for (int k = 0; k < DH; k += 4) {
        float4 w0 = *reinterpret_cast<const float4*>(WT + (size_t)(k + 0) * DH + j0);
        float4 w1 = *reinterpret_cast<const float4*>(WT + (size_t)(k + 1) * DH + j0);
        float4 w2 = *reinterpret_cast<const float4*>(WT + (size_t)(k + 2) * DH + j0);
        float4 w3 = *reinterpret_cast<const float4*>(WT + (size_t)(k + 3) * DH + j0);
#pragma unroll
        for (int n = 0; n < 8; ++n) {
            float4 av = *reinterpret_cast<const float4*>(rowbase + (size_t)n * DH + k);
            fma4(acc[n], av.x, w0);
            fma4(acc[n], av.y, w1);
            fma4(acc[n], av.z, w2);
            fma4(acc[n], av.w, w3);
        }
    }
}

template <int ACT>   // 0 = none, 1 = relu
__global__ __launch_bounds__(256) void k_gemm2(const float* __restrict__ A,
                                               const float* __restrict__ B,
                                               const float* __restrict__ WaT,
                                               const float* __restrict__ WbT,
                                               const float* __restrict__ bias,
                                               float* __restrict__ out, int N_) {
    int jt = threadIdx.x & 31;    // 32 col-groups of 4
    int rg = threadIdx.x >> 5;    // 8 row-groups of 8 rows
    int j0 = jt * 4;
    int n0 = blockIdx.x * 64 + rg * 8;
    if (n0 >= N_) return;
    float4 acc[8];
    float4 bv = *reinterpret_cast<const float4*>(bias + j0);
#pragma unroll
    for (int n = 0; n < 8; ++n) acc[n] = bv;
    gemm_pass4(A + (size_t)n0 * DH, WaT, j0, acc);
    gemm_pass4(B + (size_t)n0 * DH, WbT, j0, acc);
#pragma unroll
    for (int n = 0; n < 8; ++n) {
        float4 v = acc[n];
        if (ACT == 1) {
            v.x = fmaxf(v.x, 0.f); v.y = fmaxf(v.y, 0.f);
            v.z = fmaxf(v.z, 0.f); v.w = fmaxf(v.w, 0.f);
        }
        *reinterpret_cast<float4*>(out + (size_t)(n0 + n) * DH + j0) = v;
    }
}

// ---- RNN + normalize fused: t = tanh(H2@Wi^T+bi+bh); o = t@Wo^T+bo; out = o/max(||o||,eps)

__global__ __launch_bounds__(256) void k_rnn(const float* __restrict__ H2,
                                             const float* __restrict__ WiT,
                                             const float* __restrict__ bi,
                                             const float* __restrict__ bh,
                                             const float* __restrict__ WoT,
                                             const float* __restrict__ bo,
                                             float* __restrict__ out, int N_) {
    __shared__ float hid[64][DH];
    int jt = threadIdx.x & 31;
    int rg = threadIdx.x >> 5;
    int j0 = jt * 4;
    int n0 = blockIdx.x * 64 + rg * 8;
    bool active = (n0 < N_);
    float4 acc[8];
    if (active) {
        float4 b1 = *reinterpret_cast<const float4*>(bi + j0);
        float4 b2 = *reinterpret_cast<const float4*>(bh + j0);
        float4 bv;
        bv.x = b1.x + b2.x; bv.y = b1.y + b2.y;
        bv.z = b1.z + b2.z; bv.w = b1.w + b2.w;
#pragma unroll
        for (int n = 0; n < 8; ++n) acc[n] = bv;
        gemm_pass4(H2 + (size_t)n0 * DH, WiT, j0, acc);
#pragma unroll
        for (int n = 0; n < 8; ++n) {
            float4 t;
            t.x = tanhf(acc[n].x); t.y = tanhf(acc[n].y);
            t.z = tanhf(acc[n].z); t.w = tanhf(acc[n].w);
            *reinterpret_cast<float4*>(&hid[rg * 8 + n][j0]) = t;
        }
    }
    __syncthreads();
    if (!active) return;
    float4 bov = *reinterpret_cast<const float4*>(bo + j0);
#pragma unroll
    for (int n = 0; n < 8; ++n) acc[n] = bov;
    for (int k = 0; k < DH; k += 4) {
        float4 w0 = *reinterpret_cast<const float4*>(WoT + (size_t)(k + 0) * DH + j0);
        float4 w1 = *reinterpret_cast<const float4*>(WoT + (size_t)(k + 1) * DH + j0);
        float4 w2 = *reinterpret_cast<const float4*>(WoT + (size_t)(k + 2) * DH + j0);
        float4 w3 = *reinterpret_cast<const float4*>(WoT + (size_t)(k + 3) * DH + j0);
#pragma unroll
        for (int n = 0; n < 8; ++n) {
            float4 hv = *reinterpret_cast<const float4*>(&hid[rg * 8 + n][k]);
            fma4(acc[n], hv.x, w0);
            fma4(acc[n], hv.y, w1);
            fma4(acc[n], hv.z, w2);
            fma4(acc[n], hv.w, w3);
        }
    }
    // fused row-normalize: the 32 jt-threads of one rg are one contiguous
    // 32-lane shuffle group and jointly hold cols 0..127 of rows n0..n0+7.
#pragma unroll
    for (int n = 0; n < 8; ++n) {
        float4 v = acc[n];
        float s = v.x * v.x + v.y * v.y + v.z * v.z + v.w * v.w;
#pragma unroll
        for (int off = 16; off; off >>= 1) s += __shfl_xor(s, off, 32);
        float inv = 1.0f / fmaxf(sqrtf(s), 1e-6f);
        v.x *= inv; v.y *= inv; v.z *= inv; v.w *= inv;
        *reinterpret_cast<float4*>(out + (size_t)(n0 + n) * DH + j0) = v;
    }
}

// ---------------- decode: sigmoid(dot(normalized rows)) ----------------

__global__ __launch_bounds__(256) void k_decode(const float* __restrict__ Fn,
                                                const int* __restrict__ di,
                                                float* __restrict__ res, int Q_) {
    int q = (blockIdx.x * blockDim.x + threadIdx.x) >> 5;
    int l = threadIdx.x & 31;
    if (q >= Q_) return;
    int ia = di[q];
    int ib = di[Q_ + q];
    float4 a = *reinterpret_cast<const float4*>(Fn + (size_t)ia * DH + l * 4);
    float4 b = *reinterpret_cast<const float4*>(Fn + (size_t)ib * DH + l * 4);
    float s = a.x * b.x + a.y * b.y + a.z * b.z + a.w * b.w;
#pragma unroll
    for (int off = 16; off; off >>= 1) s += __shfl_xor(s, off, 32);
    if (l == 0) res[q] = 1.0f / (1.0f + expf(-s));
}

// ---------------- launch ----------------

extern "C" void kernel_launch(void* const* d_in, const int* in_sizes, int n_in,
                              void* d_out, int out_size, void* d_ws, size_t ws_size,
                              hipStream_t stream) {
    const float* x   = (const float*)d_in[0];
    const int*   ei  = (const int*)d_in[1];
    const int*   di  = (const int*)d_in[2];
    const float* W1l = (const float*)d_in[3];
    const float* b1l = (const float*)d_in[4];
    const float* W1r = (const float*)d_in[5];
    const float* W2l = (const float*)d_in[6];
    const float* b2l = (const float*)d_in[7];
    const float* W2r = (const float*)d_in[8];
    const float* Wi  = (const float*)d_in[9];
    const float* bi  = (const float*)d_in[10];
    // d_in[11] = Wh: unused (hidden state is zeros -> only bh contributes)
    const float* bh  = (const float*)d_in[12];
    const float* Wo  = (const float*)d_in[13];
    const float* bo  = (const float*)d_in[14];
    float* outq = (float*)d_out;

    int N_ = in_sizes[0] / DH;
    int E_ = in_sizes[1] / 2;
    int Q_ = in_sizes[2] / 2;
    int ntiles = (N_ + STILE - 1) / STILE;

    char* base = (char*)d_ws;
    size_t o = 0;
    auto alloc = [&](size_t bytes) -> void* {
        o = (o + 511) & ~(size_t)511;
        void* p = base + o;
        o += bytes;
        return p;
    };
    int*   deg    = (int*)alloc((size_t)N_ * 4);
    int*   rowptr = (int*)alloc((size_t)(N_ + 1) * 4);
    int*   cursor = (int*)alloc((size_t)N_ * 4);
    int*   col    = (int*)alloc((size_t)E_ * 4);
    int*   tsum   = (int*)alloc((size_t)1024 * 4);
    int*   toff   = (int*)alloc((size_t)1024 * 4);
    float* wt     = (float*)alloc((size_t)6 * DH * DH * 4);
    float* bufA   = (float*)alloc((size_t)N_ * DH * 4);
    float* bufB   = (float*)alloc((size_t)N_ * DH * 4);
    float* bufC   = (float*)alloc((size_t)N_ * DH * 4);

    const float* W1lT = wt + 0 * DH * DH;
    const float* W1rT = wt + 1 * DH * DH;
    const float* W2lT = wt + 2 * DH * DH;
    const float* W2rT = wt + 3 * DH * DH;
    const float* WiT  = wt + 4 * DH * DH;
    const float* WoT  = wt + 5 * DH * DH;

    hipMemsetAsync(deg, 0, (size_t)N_ * 4, stream);
    k_hist<<<8192, 256, 0, stream>>>(ei, deg, E_, N_);
    // hierarchical scan: deg -> rowptr (exclusive), cursor copy, rowptr[N]=E
    k_scan1<<<ntiles, 256, 0, stream>>>(deg, rowptr, tsum, N_);
    k_scan2<<<1, 1024, 0, stream>>>(tsum, toff, ntiles, rowptr + N_);
    k_scan3<<<ntiles, 256, 0, stream>>>(rowptr, cursor, toff, N_);
    k_scatter<<<8192, 256, 0, stream>>>(ei, cursor, col, E_, N_);
    dim3 tg(64, 6);
    k_transpose<<<tg, 256, 0, stream>>>(W1l, W1r, W2l, W2r, Wi, Wo, wt);

    // layer 1: mean-agg(x) -> bufA ; h = relu(bufA@W1l^T + b1l + x@W1r^T) -> bufB
    k_agg<<<(N_ + 7) / 8, 256, 0, stream>>>(x, rowptr, col, bufA, N_);
    k_gemm2<1><<<(N_ + 63) / 64, 256, 0, stream>>>(bufA, x, W1lT, W1rT, b1l, bufB, N_);
    // layer 2: mean-agg(h) -> bufA ; h2 = bufA@W2l^T + b2l + h@W2r^T -> bufC
    k_agg<<<(N_ + 7) / 8, 256, 0, stream>>>(bufB, rowptr, col, bufA, N_);
    k_gemm2<0><<<(N_ + 63) / 64, 256, 0, stream>>>(bufA, bufB, W2lT, W2rT, b2l, bufC, N_);
    // rnn + fused normalize -> bufB
    k_rnn<<<(N_ + 63) / 64, 256, 0, stream>>>(bufC, WiT, bi, bh, WoT, bo, bufB, N_);
    // decode -> d_out
    k_decode<<<(Q_ + 7) / 8, 256, 0, stream>>>(bufB, di, outq, Q_);
}

// Round 7
// 1157.082 us; speedup vs baseline: 1.5188x; 1.2036x over previous
//
#include <hip/hip_runtime.h>
#include <math.h>

#define DH 128
#define NXCD 8
#define STILE 1024   // scan tile: 256 threads x int4

// ---------------- bf16 helpers (bit ops only) ----------------

__device__ __forceinline__ float lo2f(unsigned w) { return __uint_as_float(w << 16); }
__device__ __forceinline__ float hi2f(unsigned w) { return __uint_as_float(w & 0xFFFF0000u); }
__device__ __forceinline__ unsigned pack2bf(float a, float b) {   // RNE
    unsigned ua = __float_as_uint(a), ub = __float_as_uint(b);
    unsigned ra = (ua + 0x7FFFu + ((ua >> 16) & 1u)) >> 16;
    unsigned rb = (ub + 0x7FFFu + ((ub >> 16) & 1u)) >> 16;
    return ra | (rb << 16);
}

// f32 -> bf16 table: each thread converts 8 floats
__global__ __launch_bounds__(256) void k_tobf(const float* __restrict__ in,
                                              uint4* __restrict__ outv, int n8) {
    int i = blockIdx.x * blockDim.x + threadIdx.x;
    if (i >= n8) return;
    const float4* p = reinterpret_cast<const float4*>(in);
    float4 a = p[i * 2], b = p[i * 2 + 1];
    uint4 w;
    w.x = pack2bf(a.x, a.y); w.y = pack2bf(a.z, a.w);
    w.z = pack2bf(b.x, b.y); w.w = pack2bf(b.z, b.w);
    outv[i] = w;
}

// ---------------- CSR build (XCD-sliced by dst range) ----------------
// Each XCD-slice handles only edges whose dst is in its 1/8 node range, so
// deg/cursor atomics and col[] writes stay in that XCD's L2 (fixed the 16x
// write amplification measured in round 2).

__global__ void k_hist(const int* __restrict__ ei, int* __restrict__ deg, int E_, int N_) {
    int slice = blockIdx.x & (NXCD - 1);
    int blk   = blockIdx.x >> 3;
    int nblk  = gridDim.x >> 3;
    int lo_n = slice * (N_ >> 3);
    int hi_n = (slice == NXCD - 1) ? N_ : lo_n + (N_ >> 3);
    const int* dsts = ei + E_;
    int E4 = E_ >> 2;
    for (int e4 = blk * blockDim.x + threadIdx.x; e4 < E4; e4 += nblk * blockDim.x) {
        int4 d4 = *reinterpret_cast<const int4*>(dsts + e4 * 4);
        if (d4.x >= lo_n && d4.x < hi_n) atomicAdd(&deg[d4.x], 1);
        if (d4.y >= lo_n && d4.y < hi_n) atomicAdd(&deg[d4.y], 1);
        if (d4.z >= lo_n && d4.z < hi_n) atomicAdd(&deg[d4.z], 1);
        if (d4.w >= lo_n && d4.w < hi_n) atomicAdd(&deg[d4.w], 1);
    }
    if (blk == 0 && threadIdx.x < (E_ & 3)) {
        int d = dsts[E4 * 4 + threadIdx.x];
        if (d >= lo_n && d < hi_n) atomicAdd(&deg[d], 1);
    }
}

// ---------------- hierarchical scan ----------------

__global__ __launch_bounds__(256) void k_scan1(const int* __restrict__ deg,
                                               int* __restrict__ excl,
                                               int* __restrict__ tsum, int N_) {
    __shared__ int wsum[4];
    int t = threadIdx.x;
    int idx = blockIdx.x * STILE + t * 4;
    int4 v = {0, 0, 0, 0};
    if (idx + 3 < N_) {
        v = *reinterpret_cast<const int4*>(deg + idx);
    } else {
        if (idx + 0 < N_) v.x = deg[idx + 0];
        if (idx + 1 < N_) v.y = deg[idx + 1];
        if (idx + 2 < N_) v.z = deg[idx + 2];
        if (idx + 3 < N_) v.w = deg[idx + 3];
    }
    int s0 = v.x, s1 = s0 + v.y, s2 = s1 + v.z, s3 = s2 + v.w;
    int lane = t & 63, w = t >> 6;
    int inc = s3;
    for (int off = 1; off < 64; off <<= 1) {
        int u = __shfl_up(inc, off, 64);
        if (lane >= off) inc += u;
    }
    if (lane == 63) wsum[w] = inc;
    __syncthreads();
    int woff = 0;
    for (int i = 0; i < w; ++i) woff += wsum[i];
    int exq = woff + inc - s3;
    int4 e;
    e.x = exq; e.y = exq + s0; e.z = exq + s1; e.w = exq + s2;
    if (idx + 3 < N_) {
        *reinterpret_cast<int4*>(excl + idx) = e;
    } else {
        if (idx + 0 < N_) excl[idx + 0] = e.x;
        if (idx + 1 < N_) excl[idx + 1] = e.y;
        if (idx + 2 < N_) excl[idx + 2] = e.z;
        if (idx + 3 < N_) excl[idx + 3] = e.w;
    }
    if (t == 255) tsum[blockIdx.x] = woff + inc;
}

__global__ void k_scan2(const int* __restrict__ tsum, int* __restrict__ toff,
                        int ntiles, int* __restrict__ rowptrN) {
    __shared__ int sh[1024];
    int t = threadIdx.x;
    int v = (t < ntiles) ? tsum[t] : 0;
    sh[t] = v;
    __syncthreads();
    for (int off = 1; off < 1024; off <<= 1) {
        int u = (t >= off) ? sh[t - off] : 0;
        __syncthreads();
        sh[t] += u;
        __syncthreads();
    }
    if (t < ntiles) toff[t] = sh[t] - v;
    if (t == 1023) *rowptrN = sh[1023];
}

__global__ __launch_bounds__(256) void k_scan3(int* __restrict__ rowptr,
                                               int* __restrict__ cursor,
                                               const int* __restrict__ toff, int N_) {
    int off = toff[blockIdx.x];
    int idx = blockIdx.x * STILE + threadIdx.x * 4;
    if (idx + 3 < N_) {
        int4 e = *reinterpret_cast<int4*>(rowptr + idx);
        e.x += off; e.y += off; e.z += off; e.w += off;
        *reinterpret_cast<int4*>(rowptr + idx) = e;
        *reinterpret_cast<int4*>(cursor + idx) = e;
    } else {
        for (int i = 0; i < 4; ++i)
            if (idx + i < N_) { int e = rowptr[idx + i] + off; rowptr[idx + i] = e; cursor[idx + i] = e; }
    }
}

__global__ void k_scatter(const int* __restrict__ ei, int* __restrict__ cursor,
                          int* __restrict__ col, int E_, int N_) {
    int slice = blockIdx.x & (NXCD - 1);
    int blk   = blockIdx.x >> 3;
    int nblk  = gridDim.x >> 3;
    int lo_n = slice * (N_ >> 3);
    int hi_n = (slice == NXCD - 1) ? N_ : lo_n + (N_ >> 3);
    const int* dsts = ei + E_;
    int E4 = E_ >> 2;
    for (int e4 = blk * blockDim.x + threadIdx.x; e4 < E4; e4 += nblk * blockDim.x) {
        int4 d4 = *reinterpret_cast<const int4*>(dsts + e4 * 4);
        int e = e4 * 4;
        if (d4.x >= lo_n && d4.x < hi_n) { int p = atomicAdd(&cursor[d4.x], 1); col[p] = ei[e + 0]; }
        if (d4.y >= lo_n && d4.y < hi_n) { int p = atomicAdd(&cursor[d4.y], 1); col[p] = ei[e + 1]; }
        if (d4.z >= lo_n && d4.z < hi_n) { int p = atomicAdd(&cursor[d4.z], 1); col[p] = ei[e + 2]; }
        if (d4.w >= lo_n && d4.w < hi_n) { int p = atomicAdd(&cursor[d4.w], 1); col[p] = ei[e + 3]; }
    }
    if (blk == 0 && threadIdx.x < (E_ & 3)) {
        int e = E4 * 4 + threadIdx.x;
        int d = dsts[e];
        if (d >= lo_n && d < hi_n) { int p = atomicAdd(&cursor[d], 1); col[p] = ei[e]; }
    }
}

// ---------------- weight transpose (WT[k][j] = W[j][k]) ----------------

__global__ void k_transpose(const float* __restrict__ w0, const float* __restrict__ w1,
                            const float* __restrict__ w2, const float* __restrict__ w3,
                            const float* __restrict__ w4, const float* __restrict__ w5,
                            float* __restrict__ wt) {
    int m = blockIdx.y;
    const float* s;
    switch (m) {
        case 0: s = w0; break; case 1: s = w1; break; case 2: s = w2; break;
        case 3: s = w3; break; case 4: s = w4; break; default: s = w5; break;
    }
    float* d = wt + (size_t)m * DH * DH;
    int t = blockIdx.x * 256 + threadIdx.x;
    int k = t & (DH - 1);
    int j = t >> 7;
    d[k * DH + j] = s[j * DH + k];
}

// ------- mean aggregation over CSR, bf16 gather table (32 lanes/node) -------
// Row = 128 bf16 = 256B; lane l reads the uint2 holding elems [4l,4l+4).
// Halves the L2-miss gather traffic that bounded round-6's k_agg (FETCH 760MB).

__global__ __launch_bounds__(256) void k_agg_bf(const uint2* __restrict__ Fv,
                                                const int* __restrict__ rowptr,
                                                const int* __restrict__ col,
                                                float* __restrict__ out, int N_) {
    int g = (blockIdx.x * blockDim.x + threadIdx.x) >> 5;
    int l = threadIdx.x & 31;
    if (g >= N_) return;
    int lo = rowptr[g], hi = rowptr[g + 1];
    float4 acc0 = {0.f, 0.f, 0.f, 0.f};
    float4 acc1 = {0.f, 0.f, 0.f, 0.f};
    float4 acc2 = {0.f, 0.f, 0.f, 0.f};
    float4 acc3 = {0.f, 0.f, 0.f, 0.f};
    int j = lo;
    for (; j + 3 < hi; j += 4) {
        int s0 = col[j], s1 = col[j + 1], s2 = col[j + 2], s3 = col[j + 3];
        uint2 v0 = Fv[(size_t)s0 * 32 + l];
        uint2 v1 = Fv[(size_t)s1 * 32 + l];
        uint2 v2 = Fv[(size_t)s2 * 32 + l];
        uint2 v3 = Fv[(size_t)s3 * 32 + l];
        acc0.x += lo2f(v0.x); acc0.y += hi2f(v0.x); acc0.z += lo2f(v0.y); acc0.w += hi2f(v0.y);
        acc1.x += lo2f(v1.x); acc1.y += hi2f(v1.x); acc1.z += lo2f(v1.y); acc1.w += hi2f(v1.y);
        acc2.x += lo2f(v2.x); acc2.y += hi2f(v2.x); acc2.z += lo2f(v2.y); acc2.w += hi2f(v2.y);
        acc3.x += lo2f(v3.x); acc3.y += hi2f(v3.x); acc3.z += lo2f(v3.y); acc3.w += hi2f(v3.y);
    }
    for (; j < hi; ++j) {
        uint2 v0 = Fv[(size_t)col[j] * 32 + l];
        acc0.x += lo2f(v0.x); acc0.y += hi2f(v0.x); acc0.z += lo2f(v0.y); acc0.w += hi2f(v0.y);
    }
    float inv = 1.0f / fmaxf((float)(hi - lo), 1.0f);
    float4 r;
    r.x = (acc0.x + acc1.x + acc2.x + acc3.x) * inv;
    r.y = (acc0.y + acc1.y + acc2.y + acc3.y) * inv;
    r.z = (acc0.z + acc1.z + acc2.z + acc3.z) * inv;
    r.w = (acc0.w + acc1.w + acc2.w + acc3.w) * inv;
    // out layout: lane l holds cols [4l, 4l+4)
    *reinterpret_cast<float4*>(out + (size_t)g * DH + l * 4) = r;
}

// ---------------- dual GEMM: 4 cols x 8 rows per thread ----------------

__device__ __forceinline__ void fma4(float4& a, float s, const float4& w) {
    a.x = fmaf(s, w.x, a.x);
    a.y = fmaf(s, w.y, a.y);
    a.z = fmaf(s, w.z, a.z);
    a.w = fmaf(s, w.w, a.w);
}

__device__ __forceinline__ void gemm_pass4(const float* __restrict__ rowbase,
                                           const float* __restrict__ WT,
                                           int j0, float4 acc[8]) {
    for (int k = 0; k < DH; k += 4) {
        float4 w0 = *reinterpret_cast<const float4*>(WT + (size_t)(k + 0) * DH + j0);
        float4 w1 = *reinterpret_cast<const float4*>(WT + (size_t)(k + 1) * DH + j0);
        float4 w2 = *reinterpret_cast<const float4*>(WT + (size_t)(k + 2) * DH + j0);
        float4 w3 = *reinterpret_cast<const float4*>(WT + (size_t)(k + 3) * DH + j0);
#pragma unroll
        for (int n = 0; n < 8; ++n) {
            float4 av = *reinterpret_cast<const float4*>(rowbase + (size_t)n * DH + k);
            fma4(acc[n], av.x, w0);
            fma4(acc[n], av.y, w1);
            fma4(acc[n], av.z, w2);
            fma4(acc[n], av.w, w3);
        }
    }
}

// B rows stored bf16 (row = 64 unsigned); broadcast loads, unpack in-register
__device__ __forceinline__ void gemm_pass4_bf(const unsigned* __restrict__ rowbase,
                                              const float* __restrict__ WT,
                                              int j0, float4 acc[8]) {
    for (int k = 0; k < DH; k += 4) {
        float4 w0 = *reinterpret_cast<const float4*>(WT + (size_t)(k + 0) * DH + j0);
        float4 w1 = *reinterpret_cast<const float4*>(WT + (size_t)(k + 1) * DH + j0);
        float4 w2 = *reinterpret_cast<const float4*>(WT + (size_t)(k + 2) * DH + j0);
        float4 w3 = *reinterpret_cast<const float4*>(WT + (size_t)(k + 3) * DH + j0);
#pragma unroll
        for (int n = 0; n < 8; ++n) {
            uint2 av2 = *reinterpret_cast<const uint2*>(rowbase + (size_t)n * 64 + (k >> 1));
            fma4(acc[n], lo2f(av2.x), w0);
            fma4(acc[n], hi2f(av2.x), w1);
            fma4(acc[n], lo2f(av2.y), w2);
            fma4(acc[n], hi2f(av2.y), w3);
        }
    }
}

template <int ACT, int BBF, int OUTBF>
__global__ __launch_bounds__(256) void k_gemm2(const float* __restrict__ A,
                                               const void* __restrict__ B,
                                               const float* __restrict__ WaT,
                                               const float* __restrict__ WbT,
                                               const float* __restrict__ bias,
                                               void* __restrict__ out, int N_) {
    int jt = threadIdx.x & 31;    // 32 col-groups of 4
    int rg = threadIdx.x >> 5;    // 8 row-groups of 8 rows
    int j0 = jt * 4;
    int n0 = blockIdx.x * 64 + rg * 8;
    if (n0 >= N_) return;
    float4 acc[8];
    float4 bv = *reinterpret_cast<const float4*>(bias + j0);
#pragma unroll
    for (int n = 0; n < 8; ++n) acc[n] = bv;
    gemm_pass4(A + (size_t)n0 * DH, WaT, j0, acc);
    if (BBF)
        gemm_pass4_bf(reinterpret_cast<const unsigned*>(B) + (size_t)n0 * 64, WbT, j0, acc);
    else
        gemm_pass4(reinterpret_cast<const float*>(B) + (size_t)n0 * DH, WbT, j0, acc);
#pragma unroll
    for (int n = 0; n < 8; ++n) {
        float4 v = acc[n];
        if (ACT == 1) {
            v.x = fmaxf(v.x, 0.f); v.y = fmaxf(v.y, 0.f);
            v.z = fmaxf(v.z, 0.f); v.w = fmaxf(v.w, 0.f);
        }
        if (OUTBF) {
            uint2 w;
            w.x = pack2bf(v.x, v.y);
            w.y = pack2bf(v.z, v.w);
            reinterpret_cast<uint2*>(out)[(size_t)(n0 + n) * 32 + jt] = w;
        } else {
            *reinterpret_cast<float4*>(reinterpret_cast<float*>(out) + (size_t)(n0 + n) * DH + j0) = v;
        }
    }
}

// ---- RNN + normalize fused; normalized output stored bf16 for decode gathers

__global__ __launch_bounds__(256) void k_rnn(const float* __restrict__ H2,
                                             const float* __restrict__ WiT,
                                             const float* __restrict__ bi,
                                             const float* __restrict__ bh,
                                             const float* __restrict__ WoT,
                                             const float* __restrict__ bo,
                                             uint2* __restrict__ outbf, int N_) {
    __shared__ float hid[64][DH];
    int jt = threadIdx.x & 31;
    int rg = threadIdx.x >> 5;
    int j0 = jt * 4;
    int n0 = blockIdx.x * 64 + rg * 8;
    bool active = (n0 < N_);
    float4 acc[8];
    if (active) {
        float4 b1 = *reinterpret_cast<const float4*>(bi + j0);
        float4 b2 = *reinterpret_cast<const float4*>(bh + j0);
        float4 bv;
        bv.x = b1.x + b2.x; bv.y = b1.y + b2.y;
        bv.z = b1.z + b2.z; bv.w = b1.w + b2.w;
#pragma unroll
        for (int n = 0; n < 8; ++n) acc[n] = bv;
        gemm_pass4(H2 + (size_t)n0 * DH, WiT, j0, acc);
#pragma unroll
        for (int n = 0; n < 8; ++n) {
            float4 t;
            t.x = tanhf(acc[n].x); t.y = tanhf(acc[n].y);
            t.z = tanhf(acc[n].z); t.w = tanhf(acc[n].w);
            *reinterpret_cast<float4*>(&hid[rg * 8 + n][j0]) = t;
        }
    }
    __syncthreads();
    if (!active) return;
    float4 bov = *reinterpret_cast<const float4*>(bo + j0);
#pragma unroll
    for (int n = 0; n < 8; ++n) acc[n] = bov;
    for (int k = 0; k < DH; k += 4) {
        float4 w0 = *reinterpret_cast<const float4*>(WoT + (size_t)(k + 0) * DH + j0);
        float4 w1 = *reinterpret_cast<const float4*>(WoT + (size_t)(k + 1) * DH + j0);
        float4 w2 = *reinterpret_cast<const float4*>(WoT + (size_t)(k + 2) * DH + j0);
        float4 w3 = *reinterpret_cast<const float4*>(WoT + (size_t)(k + 3) * DH + j0);
#pragma unroll
        for (int n = 0; n < 8; ++n) {
            float4 hv = *reinterpret_cast<const float4*>(&hid[rg * 8 + n][k]);
            fma4(acc[n], hv.x, w0);
            fma4(acc[n], hv.y, w1);
            fma4(acc[n], hv.z, w2);
            fma4(acc[n], hv.w, w3);
        }
    }
#pragma unroll
    for (int n = 0; n < 8; ++n) {
        float4 v = acc[n];
        float s = v.x * v.x + v.y * v.y + v.z * v.z + v.w * v.w;
#pragma unroll
        for (int off = 16; off; off >>= 1) s += __shfl_xor(s, off, 32);
        float inv = 1.0f / fmaxf(sqrtf(s), 1e-6f);
        v.x *= inv; v.y *= inv; v.z *= inv; v.w *= inv;
        uint2 w;
        w.x = pack2bf(v.x, v.y);
        w.y = pack2bf(v.z, v.w);
        outbf[(size_t)(n0 + n) * 32 + jt] = w;
    }
}

// ---------------- decode: sigmoid(dot(bf16 normalized rows)) ----------------

__global__ __launch_bounds__(256) void k_decode(const uint2* __restrict__ Fn,
                                                const int* __restrict__ di,
                                                float* __restrict__ res, int Q_) {
    int q = (blockIdx.x * blockDim.x + threadIdx.x) >> 5;
    int l = threadIdx.x & 31;
    if (q >= Q_) return;
    int ia = di[q];
    int ib = di[Q_ + q];
    uint2 a = Fn[(size_t)ia * 32 + l];
    uint2 b = Fn[(size_t)ib * 32 + l];
    float s = lo2f(a.x) * lo2f(b.x) + hi2f(a.x) * hi2f(b.x)
            + lo2f(a.y) * lo2f(b.y) + hi2f(a.y) * hi2f(b.y);
#pragma unroll
    for (int off = 16; off; off >>= 1) s += __shfl_xor(s, off, 32);
    if (l == 0) res[q] = 1.0f / (1.0f + expf(-s));
}

// ---------------- launch ----------------

extern "C" void kernel_launch(void* const* d_in, const int* in_sizes, int n_in,
                              void* d_out, int out_size, void* d_ws, size_t ws_size,
                              hipStream_t stream) {
    const float* x   = (const float*)d_in[0];
    const int*   ei  = (const int*)d_in[1];
    const int*   di  = (const int*)d_in[2];
    const float* W1l = (const float*)d_in[3];
    const float* b1l = (const float*)d_in[4];
    const float* W1r = (const float*)d_in[5];
    const float* W2l = (const float*)d_in[6];
    const float* b2l = (const float*)d_in[7];
    const float* W2r = (const float*)d_in[8];
    const float* Wi  = (const float*)d_in[9];
    const float* bi  = (const float*)d_in[10];
    // d_in[11] = Wh: unused (hidden state is zeros -> only bh contributes)
    const float* bh  = (const float*)d_in[12];
    const float* Wo  = (const float*)d_in[13];
    const float* bo  = (const float*)d_in[14];
    float* outq = (float*)d_out;

    int N_ = in_sizes[0] / DH;
    int E_ = in_sizes[1] / 2;
    int Q_ = in_sizes[2] / 2;
    int ntiles = (N_ + STILE - 1) / STILE;

    char* base = (char*)d_ws;
    size_t o = 0;
    auto alloc = [&](size_t bytes) -> void* {
        o = (o + 511) & ~(size_t)511;
        void* p = base + o;
        o += bytes;
        return p;
    };
    int*   deg    = (int*)alloc((size_t)N_ * 4);
    int*   rowptr = (int*)alloc((size_t)(N_ + 1) * 4);
    int*   cursor = (int*)alloc((size_t)N_ * 4);
    int*   col    = (int*)alloc((size_t)E_ * 4);
    int*   tsum   = (int*)alloc((size_t)1024 * 4);
    int*   toff   = (int*)alloc((size_t)1024 * 4);
    float* wt     = (float*)alloc((size_t)6 * DH * DH * 4);
    float* bufA   = (float*)alloc((size_t)N_ * DH * 4);       // agg output (f32)
    float* bufC   = (float*)alloc((size_t)N_ * DH * 4);       // h2 (f32)
    void*  xbf    = alloc((size_t)N_ * DH * 2);               // x bf16; reused as outbf
    void*  hbf    = alloc((size_t)N_ * DH * 2);               // h bf16

    const float* W1lT = wt + 0 * DH * DH;
    const float* W1rT = wt + 1 * DH * DH;
    const float* W2lT = wt + 2 * DH * DH;
    const float* W2rT = wt + 3 * DH * DH;
    const float* WiT  = wt + 4 * DH * DH;
    const float* WoT  = wt + 5 * DH * DH;

    hipMemsetAsync(deg, 0, (size_t)N_ * 4, stream);
    k_tobf<<<(N_ * DH / 8 + 255) / 256, 256, 0, stream>>>(x, (uint4*)xbf, N_ * DH / 8);
    k_hist<<<8192, 256, 0, stream>>>(ei, deg, E_, N_);
    k_scan1<<<ntiles, 256, 0, stream>>>(deg, rowptr, tsum, N_);
    k_scan2<<<1, 1024, 0, stream>>>(tsum, toff, ntiles, rowptr + N_);
    k_scan3<<<ntiles, 256, 0, stream>>>(rowptr, cursor, toff, N_);
    k_scatter<<<8192, 256, 0, stream>>>(ei, cursor, col, E_, N_);
    dim3 tg(64, 6);
    k_transpose<<<tg, 256, 0, stream>>>(W1l, W1r, W2l, W2r, Wi, Wo, wt);

    // layer 1: mean-agg(x_bf) -> bufA ; h = relu(bufA@W1l^T + b1l + x@W1r^T) -> hbf (bf16)
    k_agg_bf<<<(N_ + 7) / 8, 256, 0, stream>>>((const uint2*)xbf, rowptr, col, bufA, N_);
    k_gemm2<1, 0, 1><<<(N_ + 63) / 64, 256, 0, stream>>>(bufA, x, W1lT, W1rT, b1l, hbf, N_);
    // layer 2: mean-agg(hbf) -> bufA ; h2 = bufA@W2l^T + b2l + h@W2r^T -> bufC (f32)
    k_agg_bf<<<(N_ + 7) / 8, 256, 0, stream>>>((const uint2*)hbf, rowptr, col, bufA, N_);
    k_gemm2<0, 1, 0><<<(N_ + 63) / 64, 256, 0, stream>>>(bufA, hbf, W2lT, W2rT, b2l, bufC, N_);
    // rnn + fused normalize -> bf16 (reuse xbf region)
    k_rnn<<<(N_ + 63) / 64, 256, 0, stream>>>(bufC, WiT, bi, bh, WoT, bo, (uint2*)xbf, N_);
    // decode -> d_out
    k_decode<<<(Q_ + 7) / 8, 256, 0, stream>>>((const uint2*)xbf, di, outq, Q_);
}

// Round 10
// 811.402 us; speedup vs baseline: 2.1658x; 1.4260x over previous
//
#include <hip/hip_runtime.h>
#include <math.h>

#define DH 128
#define NXCD 8
#define STILE 1024

typedef __attribute__((ext_vector_type(4))) float f32x4;
typedef __attribute__((ext_vector_type(8))) short short8;

// ---------------- bf16 helpers (bit ops only, RNE) ----------------

__device__ __forceinline__ float lo2f(unsigned w) { return __uint_as_float(w << 16); }
__device__ __forceinline__ float hi2f(unsigned w) { return __uint_as_float(w & 0xFFFF0000u); }
__device__ __forceinline__ unsigned pack2bf(float a, float b) {
    unsigned ua = __float_as_uint(a), ub = __float_as_uint(b);
    unsigned ra = (ua + 0x7FFFu + ((ua >> 16) & 1u)) >> 16;
    unsigned rb = (ub + 0x7FFFu + ((ub >> 16) & 1u)) >> 16;
    return ra | (rb << 16);
}
__device__ __forceinline__ ushort bf16r(float f) {
    unsigned u = __float_as_uint(f);
    return (ushort)((u + 0x7FFFu + ((u >> 16) & 1u)) >> 16);
}

// f32 -> bf16 table: each thread converts 8 floats
__global__ __launch_bounds__(256) void k_tobf(const float* __restrict__ in,
                                              uint4* __restrict__ outv, int n8) {
    int i = blockIdx.x * blockDim.x + threadIdx.x;
    if (i >= n8) return;
    const float4* p = reinterpret_cast<const float4*>(in);
    float4 a = p[i * 2], b = p[i * 2 + 1];
    uint4 w;
    w.x = pack2bf(a.x, a.y); w.y = pack2bf(a.z, a.w);
    w.z = pack2bf(b.x, b.y); w.w = pack2bf(b.z, b.w);
    outv[i] = w;
}

// ---------------- CSR build (XCD-sliced by dst range) ----------------

__global__ void k_hist(const int* __restrict__ ei, int* __restrict__ deg, int E_, int N_) {
    int slice = blockIdx.x & (NXCD - 1);
    int blk   = blockIdx.x >> 3;
    int nblk  = gridDim.x >> 3;
    int lo_n = slice * (N_ >> 3);
    int hi_n = (slice == NXCD - 1) ? N_ : lo_n + (N_ >> 3);
    const int* dsts = ei + E_;
    int E4 = E_ >> 2;
    for (int e4 = blk * blockDim.x + threadIdx.x; e4 < E4; e4 += nblk * blockDim.x) {
        int4 d4 = *reinterpret_cast<const int4*>(dsts + e4 * 4);
        if (d4.x >= lo_n && d4.x < hi_n) atomicAdd(&deg[d4.x], 1);
        if (d4.y >= lo_n && d4.y < hi_n) atomicAdd(&deg[d4.y], 1);
        if (d4.z >= lo_n && d4.z < hi_n) atomicAdd(&deg[d4.z], 1);
        if (d4.w >= lo_n && d4.w < hi_n) atomicAdd(&deg[d4.w], 1);
    }
    if (blk == 0 && threadIdx.x < (E_ & 3)) {
        int d = dsts[E4 * 4 + threadIdx.x];
        if (d >= lo_n && d < hi_n) atomicAdd(&deg[d], 1);
    }
}

// ---------------- hierarchical scan ----------------

__global__ __launch_bounds__(256) void k_scan1(const int* __restrict__ deg,
                                               int* __restrict__ excl,
                                               int* __restrict__ tsum, int N_) {
    __shared__ int wsum[4];
    int t = threadIdx.x;
    int idx = blockIdx.x * STILE + t * 4;
    int4 v = {0, 0, 0, 0};
    if (idx + 3 < N_) {
        v = *reinterpret_cast<const int4*>(deg + idx);
    } else {
        if (idx + 0 < N_) v.x = deg[idx + 0];
        if (idx + 1 < N_) v.y = deg[idx + 1];
        if (idx + 2 < N_) v.z = deg[idx + 2];
        if (idx + 3 < N_) v.w = deg[idx + 3];
    }
    int s0 = v.x, s1 = s0 + v.y, s2 = s1 + v.z, s3 = s2 + v.w;
    int lane = t & 63, w = t >> 6;
    int inc = s3;
    for (int off = 1; off < 64; off <<= 1) {
        int u = __shfl_up(inc, off, 64);
        if (lane >= off) inc += u;
    }
    if (lane == 63) wsum[w] = inc;
    __syncthreads();
    int woff = 0;
    for (int i = 0; i < w; ++i) woff += wsum[i];
    int exq = woff + inc - s3;
    int4 e;
    e.x = exq; e.y = exq + s0; e.z = exq + s1; e.w = exq + s2;
    if (idx + 3 < N_) {
        *reinterpret_cast<int4*>(excl + idx) = e;
    } else {
        if (idx + 0 < N_) excl[idx + 0] = e.x;
        if (idx + 1 < N_) excl[idx + 1] = e.y;
        if (idx + 2 < N_) excl[idx + 2] = e.z;
        if (idx + 3 < N_) excl[idx + 3] = e.w;
    }
    if (t == 255) tsum[blockIdx.x] = woff + inc;
}

__global__ void k_scan2(const int* __restrict__ tsum, int* __restrict__ toff,
                        int ntiles, int* __restrict__ rowptrN) {
    __shared__ int sh[1024];
    int t = threadIdx.x;
    int v = (t < ntiles) ? tsum[t] : 0;
    sh[t] = v;
    __syncthreads();
    for (int off = 1; off < 1024; off <<= 1) {
        int u = (t >= off) ? sh[t - off] : 0;
        __syncthreads();
        sh[t] += u;
        __syncthreads();
    }
    if (t < ntiles) toff[t] = sh[t] - v;
    if (t == 1023) *rowptrN = sh[1023];
}

__global__ __launch_bounds__(256) void k_scan3(int* __restrict__ rowptr,
                                               int* __restrict__ cursor,
                                               const int* __restrict__ toff, int N_) {
    int off = toff[blockIdx.x];
    int idx = blockIdx.x * STILE + threadIdx.x * 4;
    if (idx + 3 < N_) {
        int4 e = *reinterpret_cast<int4*>(rowptr + idx);
        e.x += off; e.y += off; e.z += off; e.w += off;
        *reinterpret_cast<int4*>(rowptr + idx) = e;
        *reinterpret_cast<int4*>(cursor + idx) = e;
    } else {
        for (int i = 0; i < 4; ++i)
            if (idx + i < N_) { int e = rowptr[idx + i] + off; rowptr[idx + i] = e; cursor[idx + i] = e; }
    }
}

__global__ void k_scatter(const int* __restrict__ ei, int* __restrict__ cursor,
                          int* __restrict__ col, int E_, int N_) {
    int slice = blockIdx.x & (NXCD - 1);
    int blk   = blockIdx.x >> 3;
    int nblk  = gridDim.x >> 3;
    int lo_n = slice * (N_ >> 3);
    int hi_n = (slice == NXCD - 1) ? N_ : lo_n + (N_ >> 3);
    const int* dsts = ei + E_;
    int E4 = E_ >> 2;
    for (int e4 = blk * blockDim.x + threadIdx.x; e4 < E4; e4 += nblk * blockDim.x) {
        int4 d4 = *reinterpret_cast<const int4*>(dsts + e4 * 4);
        int e = e4 * 4;
        if (d4.x >= lo_n && d4.x < hi_n) { int p = atomicAdd(&cursor[d4.x], 1); col[p] = ei[e + 0]; }
        if (d4.y >= lo_n && d4.y < hi_n) { int p = atomicAdd(&cursor[d4.y], 1); col[p] = ei[e + 1]; }
        if (d4.z >= lo_n && d4.z < hi_n) { int p = atomicAdd(&cursor[d4.z], 1); col[p] = ei[e + 2]; }
        if (d4.w >= lo_n && d4.w < hi_n) { int p = atomicAdd(&cursor[d4.w], 1); col[p] = ei[e + 3]; }
    }
    if (blk == 0 && threadIdx.x < (E_ & 3)) {
        int e = E4 * 4 + threadIdx.x;
        int d = dsts[e];
        if (d >= lo_n && d < hi_n) { int p = atomicAdd(&cursor[d], 1); col[p] = ei[e]; }
    }
}

// -------- weight prep: pack W[j][k] (f32) into MFMA B-fragment bf16 order ----
// frag (m, kb, jb): lane l, elem i = B[kb*32 + (l>>4)*8 + i][jb*16 + (l&15)]
//                                  = W[jb*16 + (l&15)][kb*32 + (l>>4)*8 + i]
// flat short offset = m*16384 + kb*4096 + jb*512 + l*8

__global__ __launch_bounds__(256) void k_prepw(const float* __restrict__ w0,
                                               const float* __restrict__ w1,
                                               const float* __restrict__ w2,
                                               const float* __restrict__ w3,
                                               const float* __restrict__ w4,
                                               const float* __restrict__ w5,
                                               ushort* __restrict__ wf) {
    int t = blockIdx.x * 256 + threadIdx.x;   // 0..12287
    if (t >= 12288) return;
    int m = t >> 11;
    int rem = t & 2047;
    int kb = rem >> 9;
    int rem2 = rem & 511;
    int jb = rem2 >> 6;
    int l = rem2 & 63;
    const float* W;
    switch (m) {
        case 0: W = w0; break; case 1: W = w1; break; case 2: W = w2; break;
        case 3: W = w3; break; case 4: W = w4; break; default: W = w5; break;
    }
    int j = jb * 16 + (l & 15);
    int k0 = kb * 32 + (l >> 4) * 8;
    const float* src = W + (size_t)j * DH + k0;
    uint4 o;
    o.x = pack2bf(src[0], src[1]);
    o.y = pack2bf(src[2], src[3]);
    o.z = pack2bf(src[4], src[5]);
    o.w = pack2bf(src[6], src[7]);
    *reinterpret_cast<uint4*>(wf + (size_t)t * 8) = o;
}

// ------- mean aggregation over CSR, bf16 in / bf16 out (32 lanes/node) -------

__global__ __launch_bounds__(256) void k_agg_bf(const uint2* __restrict__ Fv,
                                                const int* __restrict__ rowptr,
                                                const int* __restrict__ col,
                                                uint2* __restrict__ out, int N_) {
    int g = (blockIdx.x * blockDim.x + threadIdx.x) >> 5;
    int l = threadIdx.x & 31;
    if (g >= N_) return;
    int lo = rowptr[g], hi = rowptr[g + 1];
    float4 acc0 = {0.f, 0.f, 0.f, 0.f};
    float4 acc1 = {0.f, 0.f, 0.f, 0.f};
    float4 acc2 = {0.f, 0.f, 0.f, 0.f};
    float4 acc3 = {0.f, 0.f, 0.f, 0.f};
    int j = lo;
    for (; j + 3 < hi; j += 4) {
        int s0 = col[j], s1 = col[j + 1], s2 = col[j + 2], s3 = col[j + 3];
        uint2 v0 = Fv[(size_t)s0 * 32 + l];
        uint2 v1 = Fv[(size_t)s1 * 32 + l];
        uint2 v2 = Fv[(size_t)s2 * 32 + l];
        uint2 v3 = Fv[(size_t)s3 * 32 + l];
        acc0.x += lo2f(v0.x); acc0.y += hi2f(v0.x); acc0.z += lo2f(v0.y); acc0.w += hi2f(v0.y);
        acc1.x += lo2f(v1.x); acc1.y += hi2f(v1.x); acc1.z += lo2f(v1.y); acc1.w += hi2f(v1.y);
        acc2.x += lo2f(v2.x); acc2.y += hi2f(v2.x); acc2.z += lo2f(v2.y); acc2.w += hi2f(v2.y);
        acc3.x += lo2f(v3.x); acc3.y += hi2f(v3.x); acc3.z += lo2f(v3.y); acc3.w += hi2f(v3.y);
    }
    for (; j < hi; ++j) {
        uint2 v0 = Fv[(size_t)col[j] * 32 + l];
        acc0.x += lo2f(v0.x); acc0.y += hi2f(v0.x); acc0.z += lo2f(v0.y); acc0.w += hi2f(v0.y);
    }
    float inv = 1.0f / fmaxf((float)(hi - lo), 1.0f);
    float rx = (acc0.x + acc1.x + acc2.x + acc3.x) * inv;
    float ry = (acc0.y + acc1.y + acc2.y + acc3.y) * inv;
    float rz = (acc0.z + acc1.z + acc2.z + acc3.z) * inv;
    float rw = (acc0.w + acc1.w + acc2.w + acc3.w) * inv;
    uint2 w;
    w.x = pack2bf(rx, ry);
    w.y = pack2bf(rz, rw);
    out[(size_t)g * 32 + l] = w;
}

// ------- MFMA dual GEMM: out = act(A@Wa^T + bias + B@Wb^T), all bf16 -------
// Wave = 16-row strip; acc = 8 col-fragments (16x16 each).
// A-frag: lane l holds A[base + (l&15)][kb*32 + (l>>4)*8 + i]  (bf16x8, 16B load)
// D: col = lane&15, row = (lane>>4)*4 + reg  [m89-verified]

template <int ACT>
__global__ __launch_bounds__(256) void k_mfma_dual(const ushort* __restrict__ A,
                                                   const ushort* __restrict__ B,
                                                   const ushort* __restrict__ WaF,
                                                   const ushort* __restrict__ WbF,
                                                   const float* __restrict__ bias,
                                                   ushort* __restrict__ out, int N_) {
    int wv = threadIdx.x >> 6;
    int l  = threadIdx.x & 63;
    int base = blockIdx.x * 64 + wv * 16;
    if (base >= N_) return;
    int l15 = l & 15, g = l >> 4;
    f32x4 acc[8];
#pragma unroll
    for (int jb = 0; jb < 8; ++jb) {
        float b = bias[jb * 16 + l15];
        acc[jb] = (f32x4){b, b, b, b};
    }
    const ushort* arow = A + (size_t)(base + l15) * DH + g * 8;
    const ushort* brow = B + (size_t)(base + l15) * DH + g * 8;
#pragma unroll
    for (int kb = 0; kb < 4; ++kb) {
        short8 aA = *reinterpret_cast<const short8*>(arow + kb * 32);
        short8 aB = *reinterpret_cast<const short8*>(brow + kb * 32);
        const ushort* wa = WaF + kb * 4096 + l * 8;
        const ushort* wb = WbF + kb * 4096 + l * 8;
#pragma unroll
        for (int jb = 0; jb < 8; ++jb) {
            short8 fa = *reinterpret_cast<const short8*>(wa + jb * 512);
            short8 fb = *reinterpret_cast<const short8*>(wb + jb * 512);
            acc[jb] = __builtin_amdgcn_mfma_f32_16x16x32_bf16(aA, fa, acc[jb], 0, 0, 0);
            acc[jb] = __builtin_amdgcn_mfma_f32_16x16x32_bf16(aB, fb, acc[jb], 0, 0, 0);
        }
    }
    ushort* orow = out + (size_t)(base + g * 4) * DH + l15;
#pragma unroll
    for (int jb = 0; jb < 8; ++jb) {
#pragma unroll
        for (int r = 0; r < 4; ++r) {
            float v = acc[jb][r];
            if (ACT) v = fmaxf(v, 0.f);
            orow[(size_t)r * DH + jb * 16] = bf16r(v);
        }
    }
}

// ------- RNN (two chained MFMA matmuls) + row-normalize, bf16 out -------
// t = tanh(H2@Wi^T + bi + bh) staged in per-wave LDS (D-layout -> A-layout),
// o = t@Wo^T + bo, out = o / max(||o||, eps).

__global__ __launch_bounds__(256) void k_rnn_mfma(const ushort* __restrict__ H2,
                                                  const ushort* __restrict__ WiF,
                                                  const float* __restrict__ bi,
                                                  const float* __restrict__ bh,
                                                  const ushort* __restrict__ WoF,
                                                  const float* __restrict__ bo,
                                                  ushort* __restrict__ out, int N_) {
    __shared__ ushort lds[4][16][136];   // pad 8 bf16: 272B row stride, 16B-aligned
    int wv = threadIdx.x >> 6;
    int l  = threadIdx.x & 63;
    int base = blockIdx.x * 64 + wv * 16;
    if (base >= N_) return;
    int l15 = l & 15, g = l >> 4;
    f32x4 acc[8];
#pragma unroll
    for (int jb = 0; jb < 8; ++jb) {
        float b = bi[jb * 16 + l15] + bh[jb * 16 + l15];
        acc[jb] = (f32x4){b, b, b, b};
    }
    const ushort* arow = H2 + (size_t)(base + l15) * DH + g * 8;
#pragma unroll
    for (int kb = 0; kb < 4; ++kb) {
        short8 a = *reinterpret_cast<const short8*>(arow + kb * 32);
        const ushort* wi = WiF + kb * 4096 + l * 8;
#pragma unroll
        for (int jb = 0; jb < 8; ++jb) {
            short8 f = *reinterpret_cast<const short8*>(wi + jb * 512);
            acc[jb] = __builtin_amdgcn_mfma_f32_16x16x32_bf16(a, f, acc[jb], 0, 0, 0);
        }
    }
    // tanh -> LDS (same-wave producer/consumer; in-order DS pipe + compiler lgkmcnt)
#pragma unroll
    for (int jb = 0; jb < 8; ++jb)
#pragma unroll
        for (int r = 0; r < 4; ++r)
            lds[wv][g * 4 + r][jb * 16 + l15] = bf16r(tanhf(acc[jb][r]));
    // second matmul
#pragma unroll
    for (int jb = 0; jb < 8; ++jb) {
        float b = bo[jb * 16 + l15];
        acc[jb] = (f32x4){b, b, b, b};
    }
#pragma unroll
    for (int kb = 0; kb < 4; ++kb) {
        short8 a = *reinterpret_cast<const short8*>(&lds[wv][l15][kb * 32 + g * 8]);
        const ushort* wo = WoF + kb * 4096 + l * 8;
#pragma unroll
        for (int jb = 0; jb < 8; ++jb) {
            short8 f = *reinterpret_cast<const short8*>(wo + jb * 512);
            acc[jb] = __builtin_amdgcn_mfma_f32_16x16x32_bf16(a, f, acc[jb], 0, 0, 0);
        }
    }
    // row-normalize: row (g*4+r) lives on the 16 lanes with this g; reduce over l15
#pragma unroll
    for (int r = 0; r < 4; ++r) {
        float ss = 0.f;
#pragma unroll
        for (int jb = 0; jb < 8; ++jb) ss += acc[jb][r] * acc[jb][r];
        ss += __shfl_xor(ss, 1);
        ss += __shfl_xor(ss, 2);
        ss += __shfl_xor(ss, 4);
        ss += __shfl_xor(ss, 8);
        float inv = 1.0f / fmaxf(sqrtf(ss), 1e-6f);
        ushort* orow = out + (size_t)(base + g * 4 + r) * DH + l15;
#pragma unroll
        for (int jb = 0; jb < 8; ++jb)
            orow[jb * 16] = bf16r(acc[jb][r] * inv);
    }
}

// ---------------- decode: sigmoid(dot(bf16 normalized rows)) ----------------

__global__ __launch_bounds__(256) void k_decode(const uint2* __restrict__ Fn,
                                                const int* __restrict__ di,
                                                float* __restrict__ res, int Q_) {
    int q = (blockIdx.x * blockDim.x + threadIdx.x) >> 5;
    int l = threadIdx.x & 31;
    if (q >= Q_) return;
    int ia = di[q];
    int ib = di[Q_ + q];
    uint2 a = Fn[(size_t)ia * 32 + l];
    uint2 b = Fn[(size_t)ib * 32 + l];
    float s = lo2f(a.x) * lo2f(b.x) + hi2f(a.x) * hi2f(b.x)
            + lo2f(a.y) * lo2f(b.y) + hi2f(a.y) * hi2f(b.y);
#pragma unroll
    for (int off = 16; off; off >>= 1) s += __shfl_xor(s, off, 32);
    if (l == 0) res[q] = 1.0f / (1.0f + expf(-s));
}

// ---------------- launch ----------------

extern "C" void kernel_launch(void* const* d_in, const int* in_sizes, int n_in,
                              void* d_out, int out_size, void* d_ws, size_t ws_size,
                              hipStream_t stream) {
    const float* x   = (const float*)d_in[0];
    const int*   ei  = (const int*)d_in[1];
    const int*   di  = (const int*)d_in[2];
    const float* W1l = (const float*)d_in[3];
    const float* b1l = (const float*)d_in[4];
    const float* W1r = (const float*)d_in[5];
    const float* W2l = (const float*)d_in[6];
    const float* b2l = (const float*)d_in[7];
    const float* W2r = (const float*)d_in[8];
    const float* Wi  = (const float*)d_in[9];
    const float* bi  = (const float*)d_in[10];
    // d_in[11] = Wh: unused (hidden state is zeros -> only bh contributes)
    const float* bh  = (const float*)d_in[12];
    const float* Wo  = (const float*)d_in[13];
    const float* bo  = (const float*)d_in[14];
    float* outq = (float*)d_out;

    int N_ = in_sizes[0] / DH;
    int E_ = in_sizes[1] / 2;
    int Q_ = in_sizes[2] / 2;
    int ntiles = (N_ + STILE - 1) / STILE;

    char* base = (char*)d_ws;
    size_t o = 0;
    auto alloc = [&](size_t bytes) -> void* {
        o = (o + 511) & ~(size_t)511;
        void* p = base + o;
        o += bytes;
        return p;
    };
    int*    deg    = (int*)alloc((size_t)N_ * 4);
    int*    rowptr = (int*)alloc((size_t)(N_ + 1) * 4);
    int*    cursor = (int*)alloc((size_t)N_ * 4);
    int*    col    = (int*)alloc((size_t)E_ * 4);
    int*    tsum   = (int*)alloc((size_t)1024 * 4);
    int*    toff   = (int*)alloc((size_t)1024 * 4);
    ushort* wf     = (ushort*)alloc((size_t)6 * 16384 * 2);
    void*   xbf    = alloc((size_t)N_ * DH * 2);
    void*   hbf    = alloc((size_t)N_ * DH * 2);
    void*   aggbf  = alloc((size_t)N_ * DH * 2);
    void*   h2bf   = alloc((size_t)N_ * DH * 2);
    void*   outbf  = alloc((size_t)N_ * DH * 2);

    hipMemsetAsync(deg, 0, (size_t)N_ * 4, stream);
    k_tobf<<<(N_ * DH / 8 + 255) / 256, 256, 0, stream>>>(x, (uint4*)xbf, N_ * DH / 8);
    k_hist<<<8192, 256, 0, stream>>>(ei, deg, E_, N_);
    k_scan1<<<ntiles, 256, 0, stream>>>(deg, rowptr, tsum, N_);
    k_scan2<<<1, 1024, 0, stream>>>(tsum, toff, ntiles, rowptr + N_);
    k_scan3<<<ntiles, 256, 0, stream>>>(rowptr, cursor, toff, N_);
    k_scatter<<<8192, 256, 0, stream>>>(ei, cursor, col, E_, N_);
    k_prepw<<<48, 256, 0, stream>>>(W1l, W1r, W2l, W2r, Wi, Wo, wf);

    int gw = (N_ + 63) / 64;
    // layer 1: mean-agg(xbf) -> aggbf ; h = relu(agg@W1l^T + b1l + x@W1r^T) -> hbf
    k_agg_bf<<<(N_ + 7) / 8, 256, 0, stream>>>((const uint2*)xbf, rowptr, col, (uint2*)aggbf, N_);
    k_mfma_dual<1><<<gw, 256, 0, stream>>>((const ushort*)aggbf, (const ushort*)xbf,
                                           wf + 0 * 16384, wf + 1 * 16384, b1l,
                                           (ushort*)hbf, N_);
    // layer 2: mean-agg(hbf) -> aggbf ; h2 = agg@W2l^T + b2l + h@W2r^T -> h2bf
    k_agg_bf<<<(N_ + 7) / 8, 256, 0, stream>>>((const uint2*)hbf, rowptr, col, (uint2*)aggbf, N_);
    k_mfma_dual<0><<<gw, 256, 0, stream>>>((const ushort*)aggbf, (const ushort*)hbf,
                                           wf + 2 * 16384, wf + 3 * 16384, b2l,
                                           (ushort*)h2bf, N_);
    // rnn + normalize -> outbf
    k_rnn_mfma<<<gw, 256, 0, stream>>>((const ushort*)h2bf, wf + 4 * 16384, bi, bh,
                                       wf + 5 * 16384, bo, (ushort*)outbf, N_);
    // decode -> d_out
    k_decode<<<(Q_ + 7) / 8, 256, 0, stream>>>((const uint2*)outbf, di, outq, Q_);
}

// Round 14
// 609.522 us; speedup vs baseline: 2.8832x; 1.3312x over previous
//
#include <hip/hip_runtime.h>
#include <math.h>

#define DH 128
#define STILE 1024
#define BBLK 256      // blocks in bucket-hist / bucket-write
#define MAXK 512      // max buckets (N <= 128K)

typedef __attribute__((ext_vector_type(4))) float f32x4;
typedef __attribute__((ext_vector_type(8))) short short8;

// ---------------- bf16 helpers (bit ops only, RNE) ----------------

__device__ __forceinline__ float lo2f(unsigned w) { return __uint_as_float(w << 16); }
__device__ __forceinline__ float hi2f(unsigned w) { return __uint_as_float(w & 0xFFFF0000u); }
__device__ __forceinline__ unsigned pack2bf(float a, float b) {
    unsigned ua = __float_as_uint(a), ub = __float_as_uint(b);
    unsigned ra = (ua + 0x7FFFu + ((ua >> 16) & 1u)) >> 16;
    unsigned rb = (ub + 0x7FFFu + ((ub >> 16) & 1u)) >> 16;
    return ra | (rb << 16);
}
__device__ __forceinline__ ushort bf16r(float f) {
    unsigned u = __float_as_uint(f);
    return (ushort)((u + 0x7FFFu + ((u >> 16) & 1u)) >> 16);
}

// f32 -> bf16 table
__global__ __launch_bounds__(256) void k_tobf(const float* __restrict__ in,
                                              uint4* __restrict__ outv, int n8) {
    int i = blockIdx.x * blockDim.x + threadIdx.x;
    if (i >= n8) return;
    const float4* p = reinterpret_cast<const float4*>(in);
    float4 a = p[i * 2], b = p[i * 2 + 1];
    uint4 w;
    w.x = pack2bf(a.x, a.y); w.y = pack2bf(a.z, a.w);
    w.z = pack2bf(b.x, b.y); w.w = pack2bf(b.z, b.w);
    outv[i] = w;
}

// ---------------- bucketed CSR build ----------------
// Round-10 PMC showed col writes amplified 14x (WRITE 181MB for 12.8MB):
// a 64B line's 16 entries arrive spread over the whole kernel while the dst
// stream flushes L2. Bucket sort clusters all writes for a 33KB col region
// into one block's lifetime.

// A: per-block histogram over K buckets (bucket = dst>>8)
__global__ __launch_bounds__(512) void k_bhist(const int* __restrict__ ei,
                                               int* __restrict__ ghist,
                                               int E_, int K) {
    __shared__ int lh[MAXK];
    int tid = threadIdx.x, blk = blockIdx.x;
    if (tid < MAXK) lh[tid] = 0;
    __syncthreads();
    const int* dsts = ei + E_;
    int E4 = E_ >> 2;
    for (int e4 = blk * 512 + tid; e4 < E4; e4 += BBLK * 512) {
        int4 d4 = *reinterpret_cast<const int4*>(dsts + e4 * 4);
        atomicAdd(&lh[d4.x >> 8], 1);
        atomicAdd(&lh[d4.y >> 8], 1);
        atomicAdd(&lh[d4.z >> 8], 1);
        atomicAdd(&lh[d4.w >> 8], 1);
    }
    if (blk == 0 && tid < (E_ & 3)) atomicAdd(&lh[dsts[(E4 << 2) + tid] >> 8], 1);
    __syncthreads();
    if (tid < K) ghist[tid * BBLK + blk] = lh[tid];
}

// ---------------- hierarchical scan (shared by ghist scan) ----------------

__global__ __launch_bounds__(256) void k_scan1(const int* __restrict__ deg,
                                               int* __restrict__ excl,
                                               int* __restrict__ tsum, int N_) {
    __shared__ int wsum[4];
    int t = threadIdx.x;
    int idx = blockIdx.x * STILE + t * 4;
    int4 v = {0, 0, 0, 0};
    if (idx + 3 < N_) {
        v = *reinterpret_cast<const int4*>(deg + idx);
    } else {
        if (idx + 0 < N_) v.x = deg[idx + 0];
        if (idx + 1 < N_) v.y = deg[idx + 1];
        if (idx + 2 < N_) v.z = deg[idx + 2];
        if (idx + 3 < N_) v.w = deg[idx + 3];
    }
    int s0 = v.x, s1 = s0 + v.y, s2 = s1 + v.z, s3 = s2 + v.w;
    int lane = t & 63, w = t >> 6;
    int inc = s3;
    for (int off = 1; off < 64; off <<= 1) {
        int u = __shfl_up(inc, off, 64);
        if (lane >= off) inc += u;
    }
    if (lane == 63) wsum[w] = inc;
    __syncthreads();
    int woff = 0;
    for (int i = 0; i < w; ++i) woff += wsum[i];
    int exq = woff + inc - s3;
    int4 e;
    e.x = exq; e.y = exq + s0; e.z = exq + s1; e.w = exq + s2;
    if (idx + 3 < N_) {
        *reinterpret_cast<int4*>(excl + idx) = e;
    } else {
        if (idx + 0 < N_) excl[idx + 0] = e.x;
        if (idx + 1 < N_) excl[idx + 1] = e.y;
        if (idx + 2 < N_) excl[idx + 2] = e.z;
        if (idx + 3 < N_) excl[idx + 3] = e.w;
    }
    if (t == 255) tsum[blockIdx.x] = woff + inc;
}

__global__ void k_scan2(const int* __restrict__ tsum, int* __restrict__ toff,
                        int ntiles, int* __restrict__ totalOut) {
    __shared__ int sh[1024];
    int t = threadIdx.x;
    int v = (t < ntiles) ? tsum[t] : 0;
    sh[t] = v;
    __syncthreads();
    for (int off = 1; off < 1024; off <<= 1) {
        int u = (t >= off) ? sh[t - off] : 0;
        __syncthreads();
        sh[t] += u;
        __syncthreads();
    }
    if (t < ntiles) toff[t] = sh[t] - v;
    if (t == 1023) *totalOut = sh[1023];
}

// single-array offset add (goff += tile offset)
__global__ __launch_bounds__(256) void k_scan3s(int* __restrict__ buf,
                                                const int* __restrict__ toff, int N_) {
    int off = toff[blockIdx.x];
    int idx = blockIdx.x * STILE + threadIdx.x * 4;
    if (idx + 3 < N_) {
        int4 e = *reinterpret_cast<int4*>(buf + idx);
        e.x += off; e.y += off; e.z += off; e.w += off;
        *reinterpret_cast<int4*>(buf + idx) = e;
    } else {
        for (int i = 0; i < 4; ++i)
            if (idx + i < N_) buf[idx + i] += off;
    }
}

// C: write (src,dst) pairs into bucket-major ebuf; per-block-per-bucket runs
// are contiguous (~32 edges = 4 lines) -> near-streaming writes.
__global__ __launch_bounds__(512) void k_bwrite(const int* __restrict__ ei,
                                                const int* __restrict__ goff,
                                                int2* __restrict__ ebuf,
                                                int E_, int K) {
    __shared__ int lcur[MAXK];
    int tid = threadIdx.x, blk = blockIdx.x;
    if (tid < K) lcur[tid] = goff[tid * BBLK + blk];
    __syncthreads();
    const int* dsts = ei + E_;
    int E4 = E_ >> 2;
    for (int e4 = blk * 512 + tid; e4 < E4; e4 += BBLK * 512) {
        int4 d4 = *reinterpret_cast<const int4*>(dsts + e4 * 4);
        int4 s4 = *reinterpret_cast<const int4*>(ei + e4 * 4);
        int p;
        p = atomicAdd(&lcur[d4.x >> 8], 1); ebuf[p] = make_int2(s4.x, d4.x);
        p = atomicAdd(&lcur[d4.y >> 8], 1); ebuf[p] = make_int2(s4.y, d4.y);
        p = atomicAdd(&lcur[d4.z >> 8], 1); ebuf[p] = make_int2(s4.z, d4.z);
        p = atomicAdd(&lcur[d4.w >> 8], 1); ebuf[p] = make_int2(s4.w, d4.w);
    }
    if (blk == 0 && tid < (E_ & 3)) {
        int e = (E4 << 2) + tid;
        int d = dsts[e];
        int p = atomicAdd(&lcur[d >> 8], 1);
        ebuf[p] = make_int2(ei[e], d);
    }
}

// D: one block per bucket: LDS deg-count + scan -> rowptr; scatter col into
// the bucket's L2-resident ~33KB region (lines fill completely -> no amp).
__global__ __launch_bounds__(256) void k_bscatter(const int2* __restrict__ ebuf,
                                                  const int* __restrict__ goff,
                                                  int* __restrict__ rowptr,
                                                  int* __restrict__ col,
                                                  int E_, int N_, int K) {
    __shared__ int ldeg[256], lrp[256], lcur[256], wsum[4];
    int b = blockIdx.x;
    int tid = threadIdx.x;
    int n0 = b << 8;
    int nn = min(256, N_ - n0);
    int estart = goff[b * BBLK];
    int eend = (b + 1 < K) ? goff[(b + 1) * BBLK] : E_;
    ldeg[tid] = 0;
    lcur[tid] = 0;
    __syncthreads();
    for (int e = estart + tid; e < eend; e += 256)
        atomicAdd(&ldeg[ebuf[e].y - n0], 1);
    __syncthreads();
    // exclusive scan of 256 counts
    int v = ldeg[tid];
    int lane = tid & 63, w = tid >> 6;
    int inc = v;
    for (int off = 1; off < 64; off <<= 1) {
        int u = __shfl_up(inc, off, 64);
        if (lane >= off) inc += u;
    }
    if (lane == 63) wsum[w] = inc;
    __syncthreads();
    int woff = 0;
    for (int i = 0; i < w; ++i) woff += wsum[i];
    int rp = estart + woff + inc - v;
    lrp[tid] = rp;
    if (tid < nn) rowptr[n0 + tid] = rp;
    __syncthreads();
    for (int e = estart + tid; e < eend; e += 256) {
        int2 pr = ebuf[e];
        int dl = pr.y - n0;
        int p = lrp[dl] + atomicAdd(&lcur[dl], 1);
        col[p] = pr.x;
    }
}

// -------- weight prep: pack W[j][k] (f32) into MFMA B-fragment bf16 order ----

__global__ __launch_bounds__(256) void k_prepw(const float* __restrict__ w0,
                                               const float* __restrict__ w1,
                                               const float* __restrict__ w2,
                                               const float* __restrict__ w3,
                                               const float* __restrict__ w4,
                                               const float* __restrict__ w5,
                                               ushort* __restrict__ wf) {
    int t = blockIdx.x * 256 + threadIdx.x;   // 0..12287
    if (t >= 12288) return;
    int m = t >> 11;
    int rem = t & 2047;
    int kb = rem >> 9;
    int rem2 = rem & 511;
    int jb = rem2 >> 6;
    int l = rem2 & 63;
    const float* W;
    switch (m) {
        case 0: W = w0; break; case 1: W = w1; break; case 2: W = w2; break;
        case 3: W = w3; break; case 4: W = w4; break; default: W = w5; break;
    }
    int j = jb * 16 + (l & 15);
    int k0 = kb * 32 + (l >> 4) * 8;
    const float* src = W + (size_t)j * DH + k0;
    uint4 o;
    o.x = pack2bf(src[0], src[1]);
    o.y = pack2bf(src[2], src[3]);
    o.z = pack2bf(src[4], src[5]);
    o.w = pack2bf(src[6], src[7]);
    *reinterpret_cast<uint4*>(wf + (size_t)t * 8) = o;
}

// ------- mean aggregation over CSR, bf16 in / bf16 out (32 lanes/node) -------

__global__ __launch_bounds__(256) void k_agg_bf(const uint2* __restrict__ Fv,
                                                const int* __restrict__ rowptr,
                                                const int* __restrict__ col,
                                                uint2* __restrict__ out, int N_) {
    int g = (blockIdx.x * blockDim.x + threadIdx.x) >> 5;
    int l = threadIdx.x & 31;
    if (g >= N_) return;
    int lo = rowptr[g], hi = rowptr[g + 1];
    float4 acc0 = {0.f, 0.f, 0.f, 0.f};
    float4 acc1 = {0.f, 0.f, 0.f, 0.f};
    float4 acc2 = {0.f, 0.f, 0.f, 0.f};
    float4 acc3 = {0.f, 0.f, 0.f, 0.f};
    int j = lo;
    for (; j + 3 < hi; j += 4) {
        int s0 = col[j], s1 = col[j + 1], s2 = col[j + 2], s3 = col[j + 3];
        uint2 v0 = Fv[(size_t)s0 * 32 + l];
        uint2 v1 = Fv[(size_t)s1 * 32 + l];
        uint2 v2 = Fv[(size_t)s2 * 32 + l];
        uint2 v3 = Fv[(size_t)s3 * 32 + l];
        acc0.x += lo2f(v0.x); acc0.y += hi2f(v0.x); acc0.z += lo2f(v0.y); acc0.w += hi2f(v0.y);
        acc1.x += lo2f(v1.x); acc1.y += hi2f(v1.x); acc1.z += lo2f(v1.y); acc1.w += hi2f(v1.y);
        acc2.x += lo2f(v2.x); acc2.y += hi2f(v2.x); acc2.z += lo2f(v2.y); acc2.w += hi2f(v2.y);
        acc3.x += lo2f(v3.x); acc3.y += hi2f(v3.x); acc3.z += lo2f(v3.y); acc3.w += hi2f(v3.y);
    }
    for (; j < hi; ++j) {
        uint2 v0 = Fv[(size_t)col[j] * 32 + l];
        acc0.x += lo2f(v0.x); acc0.y += hi2f(v0.x); acc0.z += lo2f(v0.y); acc0.w += hi2f(v0.y);
    }
    float inv = 1.0f / fmaxf((float)(hi - lo), 1.0f);
    float rx = (acc0.x + acc1.x + acc2.x + acc3.x) * inv;
    float ry = (acc0.y + acc1.y + acc2.y + acc3.y) * inv;
    float rz = (acc0.z + acc1.z + acc2.z + acc3.z) * inv;
    float rw = (acc0.w + acc1.w + acc2.w + acc3.w) * inv;
    uint2 w;
    w.x = pack2bf(rx, ry);
    w.y = pack2bf(rz, rw);
    out[(size_t)g * 32 + l] = w;
}

// ------- MFMA dual GEMM: out = act(A@Wa^T + bias + B@Wb^T), all bf16 -------

template <int ACT>
__global__ __launch_bounds__(256) void k_mfma_dual(const ushort* __restrict__ A,
                                                   const ushort* __restrict__ B,
                                                   const ushort* __restrict__ WaF,
                                                   const ushort* __restrict__ WbF,
                                                   const float* __restrict__ bias,
                                                   ushort* __restrict__ out, int N_) {
    int wv = threadIdx.x >> 6;
    int l  = threadIdx.x & 63;
    int base = blockIdx.x * 64 + wv * 16;
    if (base >= N_) return;
    int l15 = l & 15, g = l >> 4;
    f32x4 acc[8];
#pragma unroll
    for (int jb = 0; jb < 8; ++jb) {
        float b = bias[jb * 16 + l15];
        acc[jb] = (f32x4){b, b, b, b};
    }
    const ushort* arow = A + (size_t)(base + l15) * DH + g * 8;
    const ushort* brow = B + (size_t)(base + l15) * DH + g * 8;
#pragma unroll
    for (int kb = 0; kb < 4; ++kb) {
        short8 aA = *reinterpret_cast<const short8*>(arow + kb * 32);
        short8 aB = *reinterpret_cast<const short8*>(brow + kb * 32);
        const ushort* wa = WaF + kb * 4096 + l * 8;
        const ushort* wb = WbF + kb * 4096 + l * 8;
#pragma unroll
        for (int jb = 0; jb < 8; ++jb) {
            short8 fa = *reinterpret_cast<const short8*>(wa + jb * 512);
            short8 fb = *reinterpret_cast<const short8*>(wb + jb * 512);
            acc[jb] = __builtin_amdgcn_mfma_f32_16x16x32_bf16(aA, fa, acc[jb], 0, 0, 0);
            acc[jb] = __builtin_amdgcn_mfma_f32_16x16x32_bf16(aB, fb, acc[jb], 0, 0, 0);
        }
    }
    ushort* orow = out + (size_t)(base + g * 4) * DH + l15;
#pragma unroll
    for (int jb = 0; jb < 8; ++jb) {
#pragma unroll
        for (int r = 0; r < 4; ++r) {
            float v = acc[jb][r];
            if (ACT) v = fmaxf(v, 0.f);
            orow[(size_t)r * DH + jb * 16] = bf16r(v);
        }
    }
}

// ------- RNN (two chained MFMA matmuls) + row-normalize, bf16 out -------

__global__ __launch_bounds__(256) void k_rnn_mfma(const ushort* __restrict__ H2,
                                                  const ushort* __restrict__ WiF,
                                                  const float* __restrict__ bi,
                                                  const float* __restrict__ bh,
                                                  const ushort* __restrict__ WoF,
                                                  const float* __restrict__ bo,
                                                  ushort* __restrict__ out, int N_) {
    __shared__ ushort lds[4][16][136];
    int wv = threadIdx.x >> 6;
    int l  = threadIdx.x & 63;
    int base = blockIdx.x * 64 + wv * 16;
    if (base >= N_) return;
    int l15 = l & 15, g = l >> 4;
    f32x4 acc[8];
#pragma unroll
    for (int jb = 0; jb < 8; ++jb) {
        float b = bi[jb * 16 + l15] + bh[jb * 16 + l15];
        acc[jb] = (f32x4){b, b, b, b};
    }
    const ushort* arow = H2 + (size_t)(base + l15) * DH + g * 8;
#pragma unroll
    for (int kb = 0; kb < 4; ++kb) {
        short8 a = *reinterpret_cast<const short8*>(arow + kb * 32);
        const ushort* wi = WiF + kb * 4096 + l * 8;
#pragma unroll
        for (int jb = 0; jb < 8; ++jb) {
            short8 f = *reinterpret_cast<const short8*>(wi + jb * 512);
            acc[jb] = __builtin_amdgcn_mfma_f32_16x16x32_bf16(a, f, acc[jb], 0, 0, 0);
        }
    }
#pragma unroll
    for (int jb = 0; jb < 8; ++jb)
#pragma unroll
        for (int r = 0; r < 4; ++r)
            lds[wv][g * 4 + r][jb * 16 + l15] = bf16r(tanhf(acc[jb][r]));
#pragma unroll
    for (int jb = 0; jb < 8; ++jb) {
        float b = bo[jb * 16 + l15];
        acc[jb] = (f32x4){b, b, b, b};
    }
#pragma unroll
    for (int kb = 0; kb < 4; ++kb) {
        short8 a = *reinterpret_cast<const short8*>(&lds[wv][l15][kb * 32 + g * 8]);
        const ushort* wo = WoF + kb * 4096 + l * 8;
#pragma unroll
        for (int jb = 0; jb < 8; ++jb) {
            short8 f = *reinterpret_cast<const short8*>(wo + jb * 512);
            acc[jb] = __builtin_amdgcn_mfma_f32_16x16x32_bf16(a, f, acc[jb], 0, 0, 0);
        }
    }
#pragma unroll
    for (int r = 0; r < 4; ++r) {
        float ss = 0.f;
#pragma unroll
        for (int jb = 0; jb < 8; ++jb) ss += acc[jb][r] * acc[jb][r];
        ss += __shfl_xor(ss, 1);
        ss += __shfl_xor(ss, 2);
        ss += __shfl_xor(ss, 4);
        ss += __shfl_xor(ss, 8);
        float inv = 1.0f / fmaxf(sqrtf(ss), 1e-6f);
        ushort* orow = out + (size_t)(base + g * 4 + r) * DH + l15;
#pragma unroll
        for (int jb = 0; jb < 8; ++jb)
            orow[jb * 16] = bf16r(acc[jb][r] * inv);
    }
}

// ---------------- decode: sigmoid(dot(bf16 normalized rows)) ----------------

__global__ __launch_bounds__(256) void k_decode(const uint2* __restrict__ Fn,
                                                const int* __restrict__ di,
                                                float* __restrict__ res, int Q_) {
    int q = (blockIdx.x * blockDim.x + threadIdx.x) >> 5;
    int l = threadIdx.x & 31;
    if (q >= Q_) return;
    int ia = di[q];
    int ib = di[Q_ + q];
    uint2 a = Fn[(size_t)ia * 32 + l];
    uint2 b = Fn[(size_t)ib * 32 + l];
    float s = lo2f(a.x) * lo2f(b.x) + hi2f(a.x) * hi2f(b.x)
            + lo2f(a.y) * lo2f(b.y) + hi2f(a.y) * hi2f(b.y);
#pragma unroll
    for (int off = 16; off; off >>= 1) s += __shfl_xor(s, off, 32);
    if (l == 0) res[q] = 1.0f / (1.0f + expf(-s));
}

// ---------------- launch ----------------

extern "C" void kernel_launch(void* const* d_in, const int* in_sizes, int n_in,
                              void* d_out, int out_size, void* d_ws, size_t ws_size,
                              hipStream_t stream) {
    const float* x   = (const float*)d_in[0];
    const int*   ei  = (const int*)d_in[1];
    const int*   di  = (const int*)d_in[2];
    const float* W1l = (const float*)d_in[3];
    const float* b1l = (const float*)d_in[4];
    const float* W1r = (const float*)d_in[5];
    const float* W2l = (const float*)d_in[6];
    const float* b2l = (const float*)d_in[7];
    const float* W2r = (const float*)d_in[8];
    const float* Wi  = (const float*)d_in[9];
    const float* bi  = (const float*)d_in[10];
    // d_in[11] = Wh: unused (hidden state is zeros -> only bh contributes)
    const float* bh  = (const float*)d_in[12];
    const float* Wo  = (const float*)d_in[13];
    const float* bo  = (const float*)d_in[14];
    float* outq = (float*)d_out;

    int N_ = in_sizes[0] / DH;
    int E_ = in_sizes[1] / 2;
    int Q_ = in_sizes[2] / 2;
    int K  = (N_ + 255) >> 8;               // buckets of 256 dst nodes
    int GH = K * BBLK;                      // ghist elements
    int gtiles = (GH + STILE - 1) / STILE;

    char* base = (char*)d_ws;
    size_t o = 0;
    auto alloc = [&](size_t bytes) -> void* {
        o = (o + 511) & ~(size_t)511;
        void* p = base + o;
        o += bytes;
        return p;
    };
    int*    rowptr = (int*)alloc((size_t)(N_ + 1) * 4);
    int*    col    = (int*)alloc((size_t)E_ * 4);
    int*    ghist  = (int*)alloc((size_t)GH * 4);
    int*    goff   = (int*)alloc((size_t)GH * 4);
    int2*   ebuf   = (int2*)alloc((size_t)E_ * 8);
    int*    tsum   = (int*)alloc((size_t)1024 * 4);
    int*    toff   = (int*)alloc((size_t)1024 * 4);
    ushort* wf     = (ushort*)alloc((size_t)6 * 16384 * 2);
    void*   xbf    = alloc((size_t)N_ * DH * 2);
    void*   hbf    = alloc((size_t)N_ * DH * 2);
    void*   aggbf  = alloc((size_t)N_ * DH * 2);
    void*   h2bf   = alloc((size_t)N_ * DH * 2);
    void*   outbf  = alloc((size_t)N_ * DH * 2);

    k_tobf<<<(N_ * DH / 8 + 255) / 256, 256, 0, stream>>>(x, (uint4*)xbf, N_ * DH / 8);
    // bucketed CSR build
    k_bhist<<<BBLK, 512, 0, stream>>>(ei, ghist, E_, K);
    k_scan1<<<gtiles, 256, 0, stream>>>(ghist, goff, tsum, GH);
    k_scan2<<<1, 1024, 0, stream>>>(tsum, toff, gtiles, rowptr + N_);   // total = E
    k_scan3s<<<gtiles, 256, 0, stream>>>(goff, toff, GH);
    k_bwrite<<<BBLK, 512, 0, stream>>>(ei, goff, ebuf, E_, K);
    k_bscatter<<<K, 256, 0, stream>>>(ebuf, goff, rowptr, col, E_, N_, K);
    k_prepw<<<48, 256, 0, stream>>>(W1l, W1r, W2l, W2r, Wi, Wo, wf);

    int gw = (N_ + 63) / 64;
    // layer 1: mean-agg(xbf) -> aggbf ; h = relu(agg@W1l^T + b1l + x@W1r^T) -> hbf
    k_agg_bf<<<(N_ + 7) / 8, 256, 0, stream>>>((const uint2*)xbf, rowptr, col, (uint2*)aggbf, N_);
    k_mfma_dual<1><<<gw, 256, 0, stream>>>((const ushort*)aggbf, (const ushort*)xbf,
                                           wf + 0 * 16384, wf + 1 * 16384, b1l,
                                           (ushort*)hbf, N_);
    // layer 2: mean-agg(hbf) -> aggbf ; h2 = agg@W2l^T + b2l + h@W2r^T -> h2bf
    k_agg_bf<<<(N_ + 7) / 8, 256, 0, stream>>>((const uint2*)hbf, rowptr, col, (uint2*)aggbf, N_);
    k_mfma_dual<0><<<gw, 256, 0, stream>>>((const ushort*)aggbf, (const ushort*)hbf,
                                           wf + 2 * 16384, wf + 3 * 16384, b2l,
                                           (ushort*)h2bf, N_);
    // rnn + normalize -> outbf
    k_rnn_mfma<<<gw, 256, 0, stream>>>((const ushort*)h2bf, wf + 4 * 16384, bi, bh,
                                       wf + 5 * 16384, bo, (ushort*)outbf, N_);
    // decode -> d_out
    k_decode<<<(Q_ + 7) / 8, 256, 0, stream>>>((const uint2*)outbf, di, outq, Q_);
}

// Round 15
// 519.008 us; speedup vs baseline: 3.3860x; 1.1744x over previous
//
#include <hip/hip_runtime.h>
#include <math.h>

#define DH 128
#define STILE 1024
#define BBLK 256      // blocks in bucket-hist / bucket-write
#define MAXK 512      // max buckets (N <= 128K)

typedef __attribute__((ext_vector_type(4))) float f32x4;
typedef __attribute__((ext_vector_type(2))) float f32x2;
typedef __attribute__((ext_vector_type(8))) short short8;

#if __has_builtin(__builtin_amdgcn_cvt_pk_f32_fp8) && __has_builtin(__builtin_amdgcn_cvt_pk_fp8_f32)
#define HAVE_HW_FP8 1
#else
#define HAVE_HW_FP8 0
#endif

// ---------------- bf16 helpers (bit ops only, RNE) ----------------

__device__ __forceinline__ float lo2f(unsigned w) { return __uint_as_float(w << 16); }
__device__ __forceinline__ float hi2f(unsigned w) { return __uint_as_float(w & 0xFFFF0000u); }
__device__ __forceinline__ unsigned pack2bf(float a, float b) {
    unsigned ua = __float_as_uint(a), ub = __float_as_uint(b);
    unsigned ra = (ua + 0x7FFFu + ((ua >> 16) & 1u)) >> 16;
    unsigned rb = (ub + 0x7FFFu + ((ub >> 16) & 1u)) >> 16;
    return ra | (rb << 16);
}
__device__ __forceinline__ ushort bf16r(float f) {
    unsigned u = __float_as_uint(f);
    return (ushort)((u + 0x7FFFu + ((u >> 16) & 1u)) >> 16);
}

// ---------------- fp8 e4m3fn helpers ----------------
// unpack: f = as_float(((v&0x80)<<24) | ((v&0x7f)<<20)) * 2^120  (exact, incl denorms)

__device__ __forceinline__ float fp8tof(unsigned v) {
    return __uint_as_float(((v & 0x80u) << 24) | ((v & 0x7Fu) << 20)) * 0x1p120f;
}

__device__ __forceinline__ unsigned f2fp8(float f) {   // RNE, saturate to 448
    unsigned s = (__float_as_uint(f) >> 24) & 0x80u;
    float a = fabsf(f);
    if (a > 448.0f) a = 448.0f;
    if (a < 0x1p-10f) return s;
    int e = (int)((__float_as_uint(a) >> 23) & 0xFF) - 127;
    if (e < -6) {
        unsigned m = (unsigned)rintf(a * 512.0f);
        return s | m;                       // m==8 carries into exp -> 2^-6, correct
    }
    unsigned ua = __float_as_uint(a);
    unsigned em = (unsigned)(((e + 7) << 3) | ((ua >> 20) & 7u));
    unsigned rest = ua & 0xFFFFFu;
    em += (rest > 0x80000u) || (rest == 0x80000u && (em & 1u));
    if (em > 0x7Eu) em = 0x7Eu;
    return s | em;
}

__device__ __forceinline__ unsigned pack4q(float x0, float x1, float x2, float x3) {
#if HAVE_HW_FP8
    int v = __builtin_amdgcn_cvt_pk_fp8_f32(x0, x1, 0, false);
    v = __builtin_amdgcn_cvt_pk_fp8_f32(x2, x3, v, true);
    return (unsigned)v;
#else
    return f2fp8(x0) | (f2fp8(x1) << 8) | (f2fp8(x2) << 16) | (f2fp8(x3) << 24);
#endif
}

__device__ __forceinline__ void unpack4q(unsigned u, float& f0, float& f1, float& f2, float& f3) {
#if HAVE_HW_FP8
    f32x2 lo = __builtin_amdgcn_cvt_pk_f32_fp8((int)u, false);
    f32x2 hi = __builtin_amdgcn_cvt_pk_f32_fp8((int)u, true);
    f0 = lo[0]; f1 = lo[1]; f2 = hi[0]; f3 = hi[1];
#else
    f0 = fp8tof(u); f1 = fp8tof(u >> 8); f2 = fp8tof(u >> 16); f3 = fp8tof(u >> 24);
#endif
}

__device__ __forceinline__ unsigned f2q1(float v) {
#if HAVE_HW_FP8
    return (unsigned)__builtin_amdgcn_cvt_pk_fp8_f32(v, v, 0, false) & 0xFFu;
#else
    return f2fp8(v);
#endif
}

// f32 -> bf16 table + fp8 table in one pass (8 floats/thread)
__global__ __launch_bounds__(256) void k_tobf(const float* __restrict__ in,
                                              uint4* __restrict__ outbf,
                                              uint2* __restrict__ outq, int n8) {
    int i = blockIdx.x * blockDim.x + threadIdx.x;
    if (i >= n8) return;
    const float4* p = reinterpret_cast<const float4*>(in);
    float4 a = p[i * 2], b = p[i * 2 + 1];
    uint4 w;
    w.x = pack2bf(a.x, a.y); w.y = pack2bf(a.z, a.w);
    w.z = pack2bf(b.x, b.y); w.w = pack2bf(b.z, b.w);
    outbf[i] = w;
    uint2 q;
    q.x = pack4q(a.x, a.y, a.z, a.w);
    q.y = pack4q(b.x, b.y, b.z, b.w);
    outq[i] = q;
}

// bf16 table -> fp8 table (4 elems/thread)
__global__ __launch_bounds__(256) void k_bf2q(const uint2* __restrict__ inb,
                                              unsigned* __restrict__ outq, int n4) {
    int i = blockIdx.x * blockDim.x + threadIdx.x;
    if (i >= n4) return;
    uint2 v = inb[i];
    outq[i] = pack4q(lo2f(v.x), hi2f(v.x), lo2f(v.y), hi2f(v.y));
}

// ---------------- bucketed CSR build (verified round 14) ----------------

__global__ __launch_bounds__(512) void k_bhist(const int* __restrict__ ei,
                                               int* __restrict__ ghist,
                                               int E_, int K) {
    __shared__ int lh[MAXK];
    int tid = threadIdx.x, blk = blockIdx.x;
    if (tid < MAXK) lh[tid] = 0;
    __syncthreads();
    const int* dsts = ei + E_;
    int E4 = E_ >> 2;
    for (int e4 = blk * 512 + tid; e4 < E4; e4 += BBLK * 512) {
        int4 d4 = *reinterpret_cast<const int4*>(dsts + e4 * 4);
        atomicAdd(&lh[d4.x >> 8], 1);
        atomicAdd(&lh[d4.y >> 8], 1);
        atomicAdd(&lh[d4.z >> 8], 1);
        atomicAdd(&lh[d4.w >> 8], 1);
    }
    if (blk == 0 && tid < (E_ & 3)) atomicAdd(&lh[dsts[(E4 << 2) + tid] >> 8], 1);
    __syncthreads();
    if (tid < K) ghist[tid * BBLK + blk] = lh[tid];
}

__global__ __launch_bounds__(256) void k_scan1(const int* __restrict__ deg,
                                               int* __restrict__ excl,
                                               int* __restrict__ tsum, int N_) {
    __shared__ int wsum[4];
    int t = threadIdx.x;
    int idx = blockIdx.x * STILE + t * 4;
    int4 v = {0, 0, 0, 0};
    if (idx + 3 < N_) {
        v = *reinterpret_cast<const int4*>(deg + idx);
    } else {
        if (idx + 0 < N_) v.x = deg[idx + 0];
        if (idx + 1 < N_) v.y = deg[idx + 1];
        if (idx + 2 < N_) v.z = deg[idx + 2];
        if (idx + 3 < N_) v.w = deg[idx + 3];
    }
    int s0 = v.x, s1 = s0 + v.y, s2 = s1 + v.z, s3 = s2 + v.w;
    int lane = t & 63, w = t >> 6;
    int inc = s3;
    for (int off = 1; off < 64; off <<= 1) {
        int u = __shfl_up(inc, off, 64);
        if (lane >= off) inc += u;
    }
    if (lane == 63) wsum[w] = inc;
    __syncthreads();
    int woff = 0;
    for (int i = 0; i < w; ++i) woff += wsum[i];
    int exq = woff + inc - s3;
    int4 e;
    e.x = exq; e.y = exq + s0; e.z = exq + s1; e.w = exq + s2;
    if (idx + 3 < N_) {
        *reinterpret_cast<int4*>(excl + idx) = e;
    } else {
        if (idx + 0 < N_) excl[idx + 0] = e.x;
        if (idx + 1 < N_) excl[idx + 1] = e.y;
        if (idx + 2 < N_) excl[idx + 2] = e.z;
        if (idx + 3 < N_) excl[idx + 3] = e.w;
    }
    if (t == 255) tsum[blockIdx.x] = woff + inc;
}

__global__ void k_scan2(const int* __restrict__ tsum, int* __restrict__ toff,
                        int ntiles, int* __restrict__ totalOut) {
    __shared__ int sh[1024];
    int t = threadIdx.x;
    int v = (t < ntiles) ? tsum[t] : 0;
    sh[t] = v;
    __syncthreads();
    for (int off = 1; off < 1024; off <<= 1) {
        int u = (t >= off) ? sh[t - off] : 0;
        __syncthreads();
        sh[t] += u;
        __syncthreads();
    }
    if (t < ntiles) toff[t] = sh[t] - v;
    if (t == 1023) *totalOut = sh[1023];
}

__global__ __launch_bounds__(256) void k_scan3s(int* __restrict__ buf,
                                                const int* __restrict__ toff, int N_) {
    int off = toff[blockIdx.x];
    int idx = blockIdx.x * STILE + threadIdx.x * 4;
    if (idx + 3 < N_) {
        int4 e = *reinterpret_cast<int4*>(buf + idx);
        e.x += off; e.y += off; e.z += off; e.w += off;
        *reinterpret_cast<int4*>(buf + idx) = e;
    } else {
        for (int i = 0; i < 4; ++i)
            if (idx + i < N_) buf[idx + i] += off;
    }
}

__global__ __launch_bounds__(512) void k_bwrite(const int* __restrict__ ei,
                                                const int* __restrict__ goff,
                                                int2* __restrict__ ebuf,
                                                int E_, int K) {
    __shared__ int lcur[MAXK];
    int tid = threadIdx.x, blk = blockIdx.x;
    if (tid < K) lcur[tid] = goff[tid * BBLK + blk];
    __syncthreads();
    const int* dsts = ei + E_;
    int E4 = E_ >> 2;
    for (int e4 = blk * 512 + tid; e4 < E4; e4 += BBLK * 512) {
        int4 d4 = *reinterpret_cast<const int4*>(dsts + e4 * 4);
        int4 s4 = *reinterpret_cast<const int4*>(ei + e4 * 4);
        int p;
        p = atomicAdd(&lcur[d4.x >> 8], 1); ebuf[p] = make_int2(s4.x, d4.x);
        p = atomicAdd(&lcur[d4.y >> 8], 1); ebuf[p] = make_int2(s4.y, d4.y);
        p = atomicAdd(&lcur[d4.z >> 8], 1); ebuf[p] = make_int2(s4.z, d4.z);
        p = atomicAdd(&lcur[d4.w >> 8], 1); ebuf[p] = make_int2(s4.w, d4.w);
    }
    if (blk == 0 && tid < (E_ & 3)) {
        int e = (E4 << 2) + tid;
        int d = dsts[e];
        int p = atomicAdd(&lcur[d >> 8], 1);
        ebuf[p] = make_int2(ei[e], d);
    }
}

__global__ __launch_bounds__(256) void k_bscatter(const int2* __restrict__ ebuf,
                                                  const int* __restrict__ goff,
                                                  int* __restrict__ rowptr,
                                                  int* __restrict__ col,
                                                  int E_, int N_, int K) {
    __shared__ int ldeg[256], lrp[256], lcur[256], wsum[4];
    int b = blockIdx.x;
    int tid = threadIdx.x;
    int n0 = b << 8;
    int nn = min(256, N_ - n0);
    int estart = goff[b * BBLK];
    int eend = (b + 1 < K) ? goff[(b + 1) * BBLK] : E_;
    ldeg[tid] = 0;
    lcur[tid] = 0;
    __syncthreads();
    for (int e = estart + tid; e < eend; e += 256)
        atomicAdd(&ldeg[ebuf[e].y - n0], 1);
    __syncthreads();
    int v = ldeg[tid];
    int lane = tid & 63, w = tid >> 6;
    int inc = v;
    for (int off = 1; off < 64; off <<= 1) {
        int u = __shfl_up(inc, off, 64);
        if (lane >= off) inc += u;
    }
    if (lane == 63) wsum[w] = inc;
    __syncthreads();
    int woff = 0;
    for (int i = 0; i < w; ++i) woff += wsum[i];
    int rp = estart + woff + inc - v;
    lrp[tid] = rp;
    if (tid < nn) rowptr[n0 + tid] = rp;
    __syncthreads();
    for (int e = estart + tid; e < eend; e += 256) {
        int2 pr = ebuf[e];
        int dl = pr.y - n0;
        int p = lrp[dl] + atomicAdd(&lcur[dl], 1);
        col[p] = pr.x;
    }
}

// -------- weight prep: pack W[j][k] (f32) into MFMA B-fragment bf16 order ----

__global__ __launch_bounds__(256) void k_prepw(const float* __restrict__ w0,
                                               const float* __restrict__ w1,
                                               const float* __restrict__ w2,
                                               const float* __restrict__ w3,
                                               const float* __restrict__ w4,
                                               const float* __restrict__ w5,
                                               ushort* __restrict__ wf) {
    int t = blockIdx.x * 256 + threadIdx.x;   // 0..12287
    if (t >= 12288) return;
    int m = t >> 11;
    int rem = t & 2047;
    int kb = rem >> 9;
    int rem2 = rem & 511;
    int jb = rem2 >> 6;
    int l = rem2 & 63;
    const float* W;
    switch (m) {
        case 0: W = w0; break; case 1: W = w1; break; case 2: W = w2; break;
        case 3: W = w3; break; case 4: W = w4; break; default: W = w5; break;
    }
    int j = jb * 16 + (l & 15);
    int k0 = kb * 32 + (l >> 4) * 8;
    const float* src = W + (size_t)j * DH + k0;
    uint4 o;
    o.x = pack2bf(src[0], src[1]);
    o.y = pack2bf(src[2], src[3]);
    o.z = pack2bf(src[4], src[5]);
    o.w = pack2bf(src[6], src[7]);
    *reinterpret_cast<uint4*>(wf + (size_t)t * 8) = o;
}

// ------- mean aggregation over CSR, fp8 gather / bf16 out (32 lanes/node) ----
// row = 128 fp8 = 128B; lane l reads the word holding cols [4l, 4l+4).
// Halves round-14's 351MB L2-miss traffic (fabric-BW-bound at ~3.4 TB/s).

__global__ __launch_bounds__(256) void k_agg_q(const unsigned* __restrict__ Fq,
                                               const int* __restrict__ rowptr,
                                               const int* __restrict__ col,
                                               uint2* __restrict__ out, int N_) {
    int g = (blockIdx.x * blockDim.x + threadIdx.x) >> 5;
    int l = threadIdx.x & 31;
    if (g >= N_) return;
    int lo = rowptr[g], hi = rowptr[g + 1];
    float4 acc0 = {0.f, 0.f, 0.f, 0.f};
    float4 acc1 = {0.f, 0.f, 0.f, 0.f};
    float4 acc2 = {0.f, 0.f, 0.f, 0.f};
    float4 acc3 = {0.f, 0.f, 0.f, 0.f};
    int j = lo;
    for (; j + 3 < hi; j += 4) {
        int s0 = col[j], s1 = col[j + 1], s2 = col[j + 2], s3 = col[j + 3];
        unsigned v0 = Fq[(size_t)s0 * 32 + l];
        unsigned v1 = Fq[(size_t)s1 * 32 + l];
        unsigned v2 = Fq[(size_t)s2 * 32 + l];
        unsigned v3 = Fq[(size_t)s3 * 32 + l];
        float f0, f1, f2, f3;
        unpack4q(v0, f0, f1, f2, f3);
        acc0.x += f0; acc0.y += f1; acc0.z += f2; acc0.w += f3;
        unpack4q(v1, f0, f1, f2, f3);
        acc1.x += f0; acc1.y += f1; acc1.z += f2; acc1.w += f3;
        unpack4q(v2, f0, f1, f2, f3);
        acc2.x += f0; acc2.y += f1; acc2.z += f2; acc2.w += f3;
        unpack4q(v3, f0, f1, f2, f3);
        acc3.x += f0; acc3.y += f1; acc3.z += f2; acc3.w += f3;
    }
    for (; j < hi; ++j) {
        unsigned v0 = Fq[(size_t)col[j] * 32 + l];
        float f0, f1, f2, f3;
        unpack4q(v0, f0, f1, f2, f3);
        acc0.x += f0; acc0.y += f1; acc0.z += f2; acc0.w += f3;
    }
    float inv = 1.0f / fmaxf((float)(hi - lo), 1.0f);
    float rx = (acc0.x + acc1.x + acc2.x + acc3.x) * inv;
    float ry = (acc0.y + acc1.y + acc2.y + acc3.y) * inv;
    float rz = (acc0.z + acc1.z + acc2.z + acc3.z) * inv;
    float rw = (acc0.w + acc1.w + acc2.w + acc3.w) * inv;
    uint2 w;
    w.x = pack2bf(rx, ry);
    w.y = pack2bf(rz, rw);
    out[(size_t)g * 32 + l] = w;
}

// ------- MFMA dual GEMM: out = act(A@Wa^T + bias + B@Wb^T), all bf16 -------

template <int ACT>
__global__ __launch_bounds__(256) void k_mfma_dual(const ushort* __restrict__ A,
                                                   const ushort* __restrict__ B,
                                                   const ushort* __restrict__ WaF,
                                                   const ushort* __restrict__ WbF,
                                                   const float* __restrict__ bias,
                                                   ushort* __restrict__ out, int N_) {
    int wv = threadIdx.x >> 6;
    int l  = threadIdx.x & 63;
    int base = blockIdx.x * 64 + wv * 16;
    if (base >= N_) return;
    int l15 = l & 15, g = l >> 4;
    f32x4 acc[8];
#pragma unroll
    for (int jb = 0; jb < 8; ++jb) {
        float b = bias[jb * 16 + l15];
        acc[jb] = (f32x4){b, b, b, b};
    }
    const ushort* arow = A + (size_t)(base + l15) * DH + g * 8;
    const ushort* brow = B + (size_t)(base + l15) * DH + g * 8;
#pragma unroll
    for (int kb = 0; kb < 4; ++kb) {
        short8 aA = *reinterpret_cast<const short8*>(arow + kb * 32);
        short8 aB = *reinterpret_cast<const short8*>(brow + kb * 32);
        const ushort* wa = WaF + kb * 4096 + l * 8;
        const ushort* wb = WbF + kb * 4096 + l * 8;
#pragma unroll
        for (int jb = 0; jb < 8; ++jb) {
            short8 fa = *reinterpret_cast<const short8*>(wa + jb * 512);
            short8 fb = *reinterpret_cast<const short8*>(wb + jb * 512);
            acc[jb] = __builtin_amdgcn_mfma_f32_16x16x32_bf16(aA, fa, acc[jb], 0, 0, 0);
            acc[jb] = __builtin_amdgcn_mfma_f32_16x16x32_bf16(aB, fb, acc[jb], 0, 0, 0);
        }
    }
    ushort* orow = out + (size_t)(base + g * 4) * DH + l15;
#pragma unroll
    for (int jb = 0; jb < 8; ++jb) {
#pragma unroll
        for (int r = 0; r < 4; ++r) {
            float v = acc[jb][r];
            if (ACT) v = fmaxf(v, 0.f);
            orow[(size_t)r * DH + jb * 16] = bf16r(v);
        }
    }
}

// ------- RNN (two chained MFMA matmuls) + row-normalize, fp8 out -------

__global__ __launch_bounds__(256) void k_rnn_mfma(const ushort* __restrict__ H2,
                                                  const ushort* __restrict__ WiF,
                                                  const float* __restrict__ bi,
                                                  const float* __restrict__ bh,
                                                  const ushort* __restrict__ WoF,
                                                  const float* __restrict__ bo,
                                                  unsigned char* __restrict__ outq, int N_) {
    __shared__ ushort lds[4][16][136];
    int wv = threadIdx.x >> 6;
    int l  = threadIdx.x & 63;
    int base = blockIdx.x * 64 + wv * 16;
    if (base >= N_) return;
    int l15 = l & 15, g = l >> 4;
    f32x4 acc[8];
#pragma unroll
    for (int jb = 0; jb < 8; ++jb) {
        float b = bi[jb * 16 + l15] + bh[jb * 16 + l15];
        acc[jb] = (f32x4){b, b, b, b};
    }
    const ushort* arow = H2 + (size_t)(base + l15) * DH + g * 8;
#pragma unroll
    for (int kb = 0; kb < 4; ++kb) {
        short8 a = *reinterpret_cast<const short8*>(arow + kb * 32);
        const ushort* wi = WiF + kb * 4096 + l * 8;
#pragma unroll
        for (int jb = 0; jb < 8; ++jb) {
            short8 f = *reinterpret_cast<const short8*>(wi + jb * 512);
            acc[jb] = __builtin_amdgcn_mfma_f32_16x16x32_bf16(a, f, acc[jb], 0, 0, 0);
        }
    }
#pragma unroll
    for (int jb = 0; jb < 8; ++jb)
#pragma unroll
        for (int r = 0; r < 4; ++r)
            lds[wv][g * 4 + r][jb * 16 + l15] = bf16r(tanhf(acc[jb][r]));
#pragma unroll
    for (int jb = 0; jb < 8; ++jb) {
        float b = bo[jb * 16 + l15];
        acc[jb] = (f32x4){b, b, b, b};
    }
#pragma unroll
    for (int kb = 0; kb < 4; ++kb) {
        short8 a = *reinterpret_cast<const short8*>(&lds[wv][l15][kb * 32 + g * 8]);
        const ushort* wo = WoF + kb * 4096 + l * 8;
#pragma unroll
        for (int jb = 0; jb < 8; ++jb) {
            short8 f = *reinterpret_cast<const short8*>(wo + jb * 512);
            acc[jb] = __builtin_amdgcn_mfma_f32_16x16x32_bf16(a, f, acc[jb], 0, 0, 0);
        }
    }
#pragma unroll
    for (int r = 0; r < 4; ++r) {
        float ss = 0.f;
#pragma unroll
        for (int jb = 0; jb < 8; ++jb) ss += acc[jb][r] * acc[jb][r];
        ss += __shfl_xor(ss, 1);
        ss += __shfl_xor(ss, 2);
        ss += __shfl_xor(ss, 4);
        ss += __shfl_xor(ss, 8);
        float inv = 1.0f / fmaxf(sqrtf(ss), 1e-6f);
        unsigned char* orow = outq + (size_t)(base + g * 4 + r) * DH + l15;
#pragma unroll
        for (int jb = 0; jb < 8; ++jb)
            orow[jb * 16] = (unsigned char)f2q1(acc[jb][r] * inv);
    }
}

// ---------------- decode: sigmoid(dot(fp8 normalized rows)) ----------------

__global__ __launch_bounds__(256) void k_decode(const unsigned* __restrict__ Fq,
                                                const int* __restrict__ di,
                                                float* __restrict__ res, int Q_) {
    int q = (blockIdx.x * blockDim.x + threadIdx.x) >> 5;
    int l = threadIdx.x & 31;
    if (q >= Q_) return;
    int ia = di[q];
    int ib = di[Q_ + q];
    unsigned a = Fq[(size_t)ia * 32 + l];
    unsigned b = Fq[(size_t)ib * 32 + l];
    float a0, a1, a2, a3, b0, b1, b2, b3;
    unpack4q(a, a0, a1, a2, a3);
    unpack4q(b, b0, b1, b2, b3);
    float s = a0 * b0 + a1 * b1 + a2 * b2 + a3 * b3;
#pragma unroll
    for (int off = 16; off; off >>= 1) s += __shfl_xor(s, off, 32);
    if (l == 0) res[q] = 1.0f / (1.0f + expf(-s));
}

// ---------------- launch ----------------

extern "C" void kernel_launch(void* const* d_in, const int* in_sizes, int n_in,
                              void* d_out, int out_size, void* d_ws, size_t ws_size,
                              hipStream_t stream) {
    const float* x   = (const float*)d_in[0];
    const int*   ei  = (const int*)d_in[1];
    const int*   di  = (const int*)d_in[2];
    const float* W1l = (const float*)d_in[3];
    const float* b1l = (const float*)d_in[4];
    const float* W1r = (const float*)d_in[5];
    const float* W2l = (const float*)d_in[6];
    const float* b2l = (const float*)d_in[7];
    const float* W2r = (const float*)d_in[8];
    const float* Wi  = (const float*)d_in[9];
    const float* bi  = (const float*)d_in[10];
    // d_in[11] = Wh: unused (hidden state is zeros -> only bh contributes)
    const float* bh  = (const float*)d_in[12];
    const float* Wo  = (const float*)d_in[13];
    const float* bo  = (const float*)d_in[14];
    float* outq = (float*)d_out;

    int N_ = in_sizes[0] / DH;
    int E_ = in_sizes[1] / 2;
    int Q_ = in_sizes[2] / 2;
    int K  = (N_ + 255) >> 8;               // buckets of 256 dst nodes
    int GH = K * BBLK;                      // ghist elements
    int gtiles = (GH + STILE - 1) / STILE;

    char* base = (char*)d_ws;
    size_t o = 0;
    auto alloc = [&](size_t bytes) -> void* {
        o = (o + 511) & ~(size_t)511;
        void* p = base + o;
        o += bytes;
        return p;
    };
    int*    rowptr = (int*)alloc((size_t)(N_ + 1) * 4);
    int*    col    = (int*)alloc((size_t)E_ * 4);
    int*    ghist  = (int*)alloc((size_t)GH * 4);
    int*    goff   = (int*)alloc((size_t)GH * 4);
    int2*   ebuf   = (int2*)alloc((size_t)E_ * 8);
    int*    tsum   = (int*)alloc((size_t)1024 * 4);
    int*    toff   = (int*)alloc((size_t)1024 * 4);
    ushort* wf     = (ushort*)alloc((size_t)6 * 16384 * 2);
    void*   xbf    = alloc((size_t)N_ * DH * 2);
    void*   hbf    = alloc((size_t)N_ * DH * 2);
    void*   aggbf  = alloc((size_t)N_ * DH * 2);
    void*   h2bf   = alloc((size_t)N_ * DH * 2);
    void*   xq     = alloc((size_t)N_ * DH);     // fp8 gather tables
    void*   hq     = alloc((size_t)N_ * DH);
    void*   oq     = alloc((size_t)N_ * DH);

    k_tobf<<<(N_ * DH / 8 + 255) / 256, 256, 0, stream>>>(x, (uint4*)xbf, (uint2*)xq,
                                                          N_ * DH / 8);
    // bucketed CSR build
    k_bhist<<<BBLK, 512, 0, stream>>>(ei, ghist, E_, K);
    k_scan1<<<gtiles, 256, 0, stream>>>(ghist, goff, tsum, GH);
    k_scan2<<<1, 1024, 0, stream>>>(tsum, toff, gtiles, rowptr + N_);   // total = E
    k_scan3s<<<gtiles, 256, 0, stream>>>(goff, toff, GH);
    k_bwrite<<<BBLK, 512, 0, stream>>>(ei, goff, ebuf, E_, K);
    k_bscatter<<<K, 256, 0, stream>>>(ebuf, goff, rowptr, col, E_, N_, K);
    k_prepw<<<48, 256, 0, stream>>>(W1l, W1r, W2l, W2r, Wi, Wo, wf);

    int gw = (N_ + 63) / 64;
    // layer 1: mean-agg(xq) -> aggbf ; h = relu(agg@W1l^T + b1l + x@W1r^T) -> hbf
    k_agg_q<<<(N_ + 7) / 8, 256, 0, stream>>>((const unsigned*)xq, rowptr, col,
                                              (uint2*)aggbf, N_);
    k_mfma_dual<1><<<gw, 256, 0, stream>>>((const ushort*)aggbf, (const ushort*)xbf,
                                           wf + 0 * 16384, wf + 1 * 16384, b1l,
                                           (ushort*)hbf, N_);
    k_bf2q<<<(N_ * DH / 4 + 255) / 256, 256, 0, stream>>>((const uint2*)hbf,
                                                          (unsigned*)hq, N_ * DH / 4);
    // layer 2: mean-agg(hq) -> aggbf ; h2 = agg@W2l^T + b2l + h@W2r^T -> h2bf
    k_agg_q<<<(N_ + 7) / 8, 256, 0, stream>>>((const unsigned*)hq, rowptr, col,
                                              (uint2*)aggbf, N_);
    k_mfma_dual<0><<<gw, 256, 0, stream>>>((const ushort*)aggbf, (const ushort*)hbf,
                                           wf + 2 * 16384, wf + 3 * 16384, b2l,
                                           (ushort*)h2bf, N_);
    // rnn + normalize -> fp8 table
    k_rnn_mfma<<<gw, 256, 0, stream>>>((const ushort*)h2bf, wf + 4 * 16384, bi, bh,
                                       wf + 5 * 16384, bo, (unsigned char*)oq, N_);
    // decode -> d_out
    k_decode<<<(Q_ + 7) / 8, 256, 0, stream>>>((const unsigned*)oq, di, outq, Q_);
}